// Round 1
// 489.108 us; speedup vs baseline: 1.0298x; 1.0298x over previous
//
#include <hip/hip_runtime.h>

// B=64, IN=1024, OUT=1024, T=256
// syn[b,o,t] = sum_i W[o,i]*x[b,i,t]; spikes via f64 LIF scan.
//
// R11: counted-vmcnt deep pipeline on the Ozaki GEMM (T3/T4/T5 per guide).
// Triple-buffered LDS (3x24KB), depth-2 global_load_lds prefetch, raw
// s_barrier + s_waitcnt vmcnt(6) (never 0 in steady state), setprio(1)
// around the 21-MFMA cluster. launch_bounds (256,2): 72KB LDS -> 2 blocks/CU.
// Numerics identical to R10 (6 digits, p+q<=5; proven R9). Fragment-ordered
// wsl/xsl (R8: zero bank conflicts), DMA dest = wave-uniform base + lane*16.
// D-placement decoded by runtime probes. Fallback: R6 f64-MFMA path.

#define B_DIM 64
#define IN_DIM 1024
#define OUT_DIM 1024
#define T_DIM 256

typedef int v4i __attribute__((ext_vector_type(4)));
typedef int v16i __attribute__((ext_vector_type(16)));
typedef double v4d __attribute__((ext_vector_type(4)));

// ---------------- workspace layout (bytes) ----------------
#define LO_OFF   0ull                    // 67108864  f32 syn_lo
#define WSL_OFF  67108864ull             // 6291456   i8 W frags [6][o32:32][ks:32][lane:64][16]
#define XSL_OFF  73400320ull             // 100663296 i8 x frags [6][b:64][t32:8][ks:32][lane:64][16]
#define AL_OFF   174063616ull            // 4096      i32 alpha_e[1024]
#define BE_OFF   174067712ull            // 65536     i32 beta_e[64][256]
#define PART_OFF 174133248ull            // 1048576   f32 partial maxes [64][16][256]
#define WS_NEED  175181824ull

__device__ __forceinline__ void gload_lds16(const void* g, void* l)
{
    __builtin_amdgcn_global_load_lds(
        (const __attribute__((address_space(1))) void*)g,
        (__attribute__((address_space(3))) void*)l, 16, 0, 0);
}

// ---------------- K1a: partial column maxes (proven) ----------------
__global__ __launch_bounds__(256) void k_beta_part(const float* __restrict__ x,
                                                   float* __restrict__ part)
{
    const int ic = blockIdx.x;   // i chunk 0..15
    const int b  = blockIdx.y;
    const int t  = threadIdx.x;
    const float* p = x + ((size_t)b * IN_DIM + ic * 64) * T_DIM + t;
    float m = 0.f;
    #pragma unroll 4
    for (int i = 0; i < 64; ++i) m = fmaxf(m, fabsf(p[(size_t)i * T_DIM]));
    part[((size_t)b * 16 + ic) * T_DIM + t] = m;
}

// ---------------- K1b: beta exponents (proven) ----------------
__global__ __launch_bounds__(256) void k_beta(const float* __restrict__ part,
                                              int* __restrict__ beta_e)
{
    const int b = blockIdx.x, t = threadIdx.x;
    float m = 0.f;
    #pragma unroll
    for (int ic = 0; ic < 16; ++ic)
        m = fmaxf(m, part[((size_t)b * 16 + ic) * T_DIM + t]);
    int e = 0;
    if (m > 0.f) frexpf(m, &e);   // |x|/2^e < 1
    beta_e[b * T_DIM + t] = e;
}

// ---------------- K2: slice x -> fragment order (proven R8) ----------------
__global__ __launch_bounds__(256) void k_slice_x(const float* __restrict__ x,
    const int* __restrict__ beta_e, signed char* __restrict__ xsl)
{
    __shared__ float ft[64][65];
    const int tb = blockIdx.x;    // 0..3
    const int ib = blockIdx.y;    // 0..15
    const int b  = blockIdx.z;
    const int tid = threadIdx.x;
    const int t0 = tb * 64, i0 = ib * 64;
    #pragma unroll
    for (int p = 0; p < 16; ++p) {
        int id = tid + p * 256;
        int il = id >> 6, tl = id & 63;
        ft[il][tl] = x[((size_t)b * IN_DIM + i0 + il) * T_DIM + t0 + tl];
    }
    __syncthreads();

    const int t32l = tid >> 7;
    const int ksl  = (tid >> 6) & 1;
    const int lane = tid & 63;
    const int t_local = t32l * 32 + (lane & 31);
    const int k_local = ksl * 32 + (lane >> 5) * 16;
    const int e = beta_e[b * T_DIM + t0 + t_local];

    signed char dig[16][6];
    #pragma unroll
    for (int j = 0; j < 16; ++j) {
        double r = ldexp((double)ft[k_local + j][t_local], -e);  // exact dyadic
        #pragma unroll
        for (int p = 0; p < 6; ++p) {
            r *= 128.0;              // exact
            double d = trunc(r);     // digit in [-127,127]
            r -= d;                  // exact
            dig[j][p] = (signed char)(int)d;
        }
    }
    #pragma unroll
    for (int p = 0; p < 6; ++p) {
        int w[4];
        #pragma unroll
        for (int g = 0; g < 4; ++g)
            w[g] = (dig[4*g][p] & 0xff) | ((dig[4*g+1][p] & 0xff) << 8) |
                   ((dig[4*g+2][p] & 0xff) << 16) | ((dig[4*g+3][p] & 0xff) << 24);
        const size_t base =
            ((((size_t)p * B_DIM + b) * 8 + (tb * 2 + t32l)) * 32 + (ib * 2 + ksl)) * 1024
            + lane * 16;
        *(v4i*)&xsl[base] = (v4i){w[0], w[1], w[2], w[3]};
    }
}

// ---------------- K3: alpha + slice W -> fragment order (proven R8) --------
__global__ __launch_bounds__(256) void k_slice_w(const float* __restrict__ W,
    signed char* __restrict__ wsl, int* __restrict__ alpha_e)
{
    __shared__ float red[256];
    __shared__ float wrow[1024];
    __shared__ int se;
    const int o = blockIdx.x, tid = threadIdx.x;
    float4 v = *(const float4*)&W[(size_t)o * IN_DIM + tid * 4];
    *(float4*)&wrow[tid * 4] = v;
    float m = fmaxf(fmaxf(fabsf(v.x), fabsf(v.y)), fmaxf(fabsf(v.z), fabsf(v.w)));
    red[tid] = m; __syncthreads();
    for (int s = 128; s > 0; s >>= 1) {
        if (tid < s) red[tid] = fmaxf(red[tid], red[tid + s]);
        __syncthreads();
    }
    if (tid == 0) { int e = 0; if (red[0] > 0.f) frexpf(red[0], &e); se = e; alpha_e[o] = e; }
    __syncthreads();
    if (tid >= 64) return;
    const int e = se;
    const int ks = tid >> 1, khalf = tid & 1;
    const int k0 = tid * 16;
    const int lane = (o & 31) + 32 * khalf;

    signed char dig[16][6];
    #pragma unroll
    for (int j = 0; j < 16; ++j) {
        double r = ldexp((double)wrow[k0 + j], -e);
        #pragma unroll
        for (int p = 0; p < 6; ++p) {
            r *= 128.0; double d = trunc(r); r -= d;
            dig[j][p] = (signed char)(int)d;
        }
    }
    #pragma unroll
    for (int p = 0; p < 6; ++p) {
        int w[4];
        #pragma unroll
        for (int g = 0; g < 4; ++g)
            w[g] = (dig[4*g][p] & 0xff) | ((dig[4*g+1][p] & 0xff) << 8) |
                   ((dig[4*g+2][p] & 0xff) << 16) | ((dig[4*g+3][p] & 0xff) << 24);
        const size_t base =
            (((size_t)p * 32 + (o >> 5)) * 32 + ks) * 1024 + lane * 16;
        *(v4i*)&wsl[base] = (v4i){w[0], w[1], w[2], w[3]};
    }
}

// ---------------- K4: Ozaki i8 MFMA GEMM (depth-2 counted-vmcnt pipeline) --
// Block 64(o)x64(t), 4 waves 2x2 of 32x32. BK=32 (one MFMA k-step), 32 steps.
// Buffer: A [p:6][h:2][lane:64][16] = 12 KB at 0; B same at 12288. x3 buffers.
// Per k-step each thread issues 6 global_load_lds (3 A + 3 B, 16B each).
// Steady state: 12 outstanding -> s_waitcnt vmcnt(6) retires the oldest tile
// while the newest stays in flight ACROSS the raw s_barrier (T4). Buffer
// hazard: step kt writes LB[(kt+2)%3], reads LB[kt%3]; the written buffer
// was last read at kt-1 whose barrier precedes this issue.
#define OZ_LOADS(PF)                                                        \
    _Pragma("unroll")                                                       \
    for (int j = 0; j < 3; ++j) {                                           \
        gload_lds16(aG[j], &LB[PF][j * 4096 + aL]);                         \
        gload_lds16(bG[j], &LB[PF][j * 4096 + bL]);                         \
        aG[j] += 1024; bG[j] += 1024;                                       \
    }

#define OZ_MATH(CUR)                                                        \
    {                                                                       \
        const signed char* base_ = LB[CUR];                                 \
        v4i bf[6];                                                          \
        _Pragma("unroll")                                                   \
        for (int q = 0; q < 6; ++q)                                         \
            bf[q] = *(const v4i*)(base_ + 12288 + q * 2048 + wth * 1024 + l16); \
        __builtin_amdgcn_s_setprio(1);                                      \
        _Pragma("unroll")                                                   \
        for (int p = 0; p < 6; ++p) {                                       \
            v4i af = *(const v4i*)(base_ + p * 2048 + woh * 1024 + l16);    \
            _Pragma("unroll")                                               \
            for (int q = 0; q < 6; ++q)                                     \
                if (p + q <= 5)                                             \
                    acc[p + q] = __builtin_amdgcn_mfma_i32_32x32x32_i8(     \
                        af, bf[q], acc[p + q], 0, 0, 0);                    \
        }                                                                   \
        __builtin_amdgcn_s_setprio(0);                                      \
    }

#define VMBAR(N)                                                            \
    do {                                                                    \
        asm volatile("s_waitcnt vmcnt(" #N ")" ::: "memory");               \
        __builtin_amdgcn_s_barrier();                                       \
    } while (0)

__global__ __launch_bounds__(256, 2) void k_oz_gemm(
    const signed char* __restrict__ wsl, const signed char* __restrict__ xsl,
    const int* __restrict__ alpha_e, const int* __restrict__ beta_e,
    float* __restrict__ syn_hi, float* __restrict__ syn_lo)
{
    __shared__ __align__(16) signed char LB[3][24576];

    const int tid = threadIdx.x;
    const int lane = tid & 63, wave = tid >> 6;
    const int tb = blockIdx.x;   // 0..3
    const int ob = blockIdx.y;   // 0..15
    const int b  = blockIdx.z;
    const int o0 = ob * 64, t0 = tb * 64;
    const int woh = wave >> 1;   // o half (0/1)
    const int wth = wave & 1;    // t half (0/1)

    v16i acc[6];
    #pragma unroll
    for (int s = 0; s < 6; ++s)
        acc[s] = (v16i){0,0,0,0,0,0,0,0,0,0,0,0,0,0,0,0};

    // Staging: unit u = 256*j + tid (j=0..5). j<3 -> A slice 2j+sh2, half sks;
    // j>=3 -> B slice 2(j-3)+sh2, half sks. LDS off u*16; DMA base uniform/wave.
    const int sh2 = (tid >> 7) & 1;
    const int sks = (tid >> 6) & 1;
    const int l16 = (tid & 63) * 16;

    const signed char* aG[3];
    const signed char* bG[3];
    #pragma unroll
    for (int j = 0; j < 3; ++j) {
        aG[j] = wsl + ((size_t)(2 * j + sh2) << 20)
                    + ((size_t)(2 * ob + sks) << 15) + l16;
        bG[j] = xsl + ((size_t)(2 * j + sh2) << 24) + ((size_t)b << 18)
                    + ((size_t)(2 * tb + sks) << 15) + l16;
    }
    const int aL = wave * 1024;          // + j*4096 (+ buffer base)
    const int bL = 12288 + wave * 1024;

    // prologue: kt=0 -> LB[0], kt=1 -> LB[1]; retire kt=0 (vmcnt 12->6).
    OZ_LOADS(0)
    OZ_LOADS(1)
    VMBAR(6);

    // steady state: kt = 0..29, buffers rotate (0,1,2). Never drain to 0.
    #pragma unroll 1
    for (int it = 0; it < 10; ++it) {
        OZ_LOADS(2) OZ_MATH(0) VMBAR(6);
        OZ_LOADS(0) OZ_MATH(1) VMBAR(6);
        OZ_LOADS(1) OZ_MATH(2) VMBAR(6);
    }
    // kt=30: nothing left to issue; drain kt=31's 6 loads, last barrier.
    OZ_MATH(0) VMBAR(0);
    // kt=31: registers only from here on.
    OZ_MATH(1)

    // Runtime D-placement probes (R6/R7 technique).
    const int lr = lane & 31;
    const int rv = (lr + 1) * 0x01010101;
    const v4i pav  = {rv, rv, rv, rv};
    const v4i onev = {0x01010101, 0x01010101, 0x01010101, 0x01010101};
    const v16i z = (v16i){0,0,0,0,0,0,0,0,0,0,0,0,0,0,0,0};
    v16i d1 = __builtin_amdgcn_mfma_i32_32x32x32_i8(pav, onev, z, 0, 0, 0);
    v16i d2 = __builtin_amdgcn_mfma_i32_32x32x32_i8(onev, pav, z, 0, 0, 0);

    const int col = (d2[0] >> 5) - 1;            // 0..31 within tile
    const int gt = t0 + wth * 32 + col;
    const int eb = beta_e[b * T_DIM + gt];
    float* ohi = syn_hi + ((size_t)b * OUT_DIM + o0) * T_DIM + gt;
    float* olo = syn_lo + ((size_t)b * OUT_DIM + o0) * T_DIM + gt;

    const double C0 = 0x1p-14, C1 = 0x1p-21, C2 = 0x1p-28, C3 = 0x1p-35,
                 C4 = 0x1p-42, C5 = 0x1p-49;
    #pragma unroll
    for (int r = 0; r < 16; ++r) {
        const int row = (d1[r] >> 5) - 1;        // 0..31 within tile
        const int go = woh * 32 + row;
        const int ea = alpha_e[o0 + go];
        double v = (double)acc[0][r] * C0 + (double)acc[1][r] * C1 +
                   (double)acc[2][r] * C2 + (double)acc[3][r] * C3 +
                   (double)acc[4][r] * C4 + (double)acc[5][r] * C5;
        double syn = ldexp(v, ea + eb);
        float hi = (float)syn;
        float lo = (float)(syn - (double)hi);
        ohi[(size_t)go * T_DIM] = hi;
        olo[(size_t)go * T_DIM] = lo;
    }
}

// ---------------- Fallback GEMM: R6 f64-MFMA with probes (proven) ----------
#define BM 128
#define BN 128
#define BK 16
#define LDA 130

__global__ __launch_bounds__(256, 2) void spk_gemm_mfma64p_kernel(
    const float* __restrict__ x, const float* __restrict__ W,
    float* __restrict__ syn_hi, float* __restrict__ syn_lo)
{
    const int tid  = threadIdx.x;
    const int lane = tid & 63;
    const int wave = tid >> 6;
    const int tb = blockIdx.x, ob = blockIdx.y, b = blockIdx.z;

    __shared__ __align__(16) double As[BK][LDA];
    __shared__ __align__(16) double Bs[BK][LDA];

    const v4d zz = {0.0, 0.0, 0.0, 0.0};
    v4d d1 = __builtin_amdgcn_mfma_f64_16x16x4f64((double)lane, 1.0, zz, 0, 0, 0);
    v4d d2 = __builtin_amdgcn_mfma_f64_16x16x4f64(1.0, (double)lane, zz, 0, 0, 0);
    const bool a_h1 = (((int)d1[0] & 3) == 0);
    const bool b_h1 = (((int)d2[0] & 3) == 0);
    int drow[4];
    #pragma unroll
    for (int r = 0; r < 4; ++r) {
        const int v = (int)d1[r];
        drow[r] = (a_h1 ? (v - 96) >> 2 : (v - 6) >> 4) & 15;
    }
    const int am = a_h1 ? (lane & 15) : (lane >> 2);
    const int ak = a_h1 ? (lane >> 4) : (lane & 3);
    const int bn = b_h1 ? (lane & 15) : (lane >> 2);
    const int bk = b_h1 ? (lane >> 4) : (lane & 3);
    const int dcol = lane & 15;

    const int o0 = ob * BM, t0 = tb * BN;
    const float* Wp = W + (size_t)o0 * IN_DIM;
    const float* xp = x + (size_t)b * IN_DIM * T_DIM + t0;
    const int wo = (wave >> 1) * 64, wt = (wave & 1) * 64;

    v4d acc[4][4];
    #pragma unroll
    for (int i = 0; i < 4; ++i)
        #pragma unroll
        for (int j = 0; j < 4; ++j) acc[i][j] = zz;

    const int ar0 = tid / 4, ac = (tid % 4) * 4;
    const int bkr0 = tid / 32, btc = (tid % 32) * 4;

    float4 pa[2], pb[2];
    #pragma unroll
    for (int p = 0; p < 2; ++p) {
        pa[p] = *(const float4*)&Wp[(size_t)(ar0 + p * 64) * IN_DIM + ac];
        pb[p] = *(const float4*)&xp[(size_t)(bkr0 + p * 8) * T_DIM + btc];
    }

    for (int k0 = 0; k0 < IN_DIM; k0 += BK) {
        #pragma unroll
        for (int p = 0; p < 2; ++p) {
            const int r = ar0 + p * 64;
            As[ac + 0][r] = (double)pa[p].x; As[ac + 1][r] = (double)pa[p].y;
            As[ac + 2][r] = (double)pa[p].z; As[ac + 3][r] = (double)pa[p].w;
            const int kr = bkr0 + p * 8;
            Bs[kr][btc + 0] = (double)pb[p].x; Bs[kr][btc + 1] = (double)pb[p].y;
            Bs[kr][btc + 2] = (double)pb[p].z; Bs[kr][btc + 3] = (double)pb[p].w;
        }
        if (k0 + BK < IN_DIM) {
            #pragma unroll
            for (int p = 0; p < 2; ++p) {
                pa[p] = *(const float4*)&Wp[(size_t)(ar0 + p * 64) * IN_DIM + k0 + BK + ac];
                pb[p] = *(const float4*)&xp[(size_t)(bkr0 + p * 8 + k0 + BK) * T_DIM + btc];
            }
        }
        __syncthreads();
        #pragma unroll
        for (int kk = 0; kk < 4; ++kk) {
            const int kra = kk * 4 + ak, krb = kk * 4 + bk;
            double a[4], bb[4];
            #pragma unroll
            for (int i = 0; i < 4; ++i) a[i] = As[kra][wo + i * 16 + am];
            #pragma unroll
            for (int j = 0; j < 4; ++j) bb[j] = Bs[krb][wt + j * 16 + bn];
            #pragma unroll
            for (int i = 0; i < 4; ++i)
                #pragma unroll
                for (int j = 0; j < 4; ++j)
                    acc[i][j] = __builtin_amdgcn_mfma_f64_16x16x4f64(a[i], bb[j], acc[i][j], 0, 0, 0);
        }
        __syncthreads();
    }

    float* ohi = syn_hi + ((size_t)b * OUT_DIM + o0) * T_DIM + t0;
    float* olo = syn_lo + ((size_t)b * OUT_DIM + o0) * T_DIM + t0;
    #pragma unroll
    for (int i = 0; i < 4; ++i)
        #pragma unroll
        for (int j = 0; j < 4; ++j) {
            const int col = wt + j * 16 + dcol;
            #pragma unroll
            for (int r = 0; r < 4; ++r) {
                double s = acc[i][j][r];
                float hi = (float)s;
                float lo = (float)(s - (double)hi);
                const size_t off = (size_t)(wo + i * 16 + drow[r]) * T_DIM + col;
                ohi[off] = hi; olo[off] = lo;
            }
        }
}

// ---------------- scan: f64 LIF, in place over hi (proven) ----------------
__global__ __launch_bounds__(256) void spk_scan_f64_kernel(
    float* __restrict__ hi, const float* __restrict__ lo)
{
    const int TC = 16;
    __shared__ float thi[256][TC + 1];
    __shared__ float tlo[256][TC + 1];
    const int tid = threadIdx.x;
    const size_t row0 = (size_t)blockIdx.x * 256;

    double mem = 0.0;
    for (int t0 = 0; t0 < T_DIM; t0 += TC) {
        #pragma unroll
        for (int p = 0; p < 4; ++p) {
            int id = tid + p * 256;
            int r = id / 4, c = (id % 4) * 4;
            size_t g = (row0 + r) * T_DIM + t0 + c;
            float4 vh = *(const float4*)&hi[g];
            thi[r][c] = vh.x; thi[r][c+1] = vh.y; thi[r][c+2] = vh.z; thi[r][c+3] = vh.w;
            float4 vl = *(const float4*)&lo[g];
            tlo[r][c] = vl.x; tlo[r][c+1] = vl.y; tlo[r][c+2] = vl.z; tlo[r][c+3] = vl.w;
        }
        __syncthreads();
        float spk[TC];
        #pragma unroll
        for (int t = 0; t < TC; ++t) {
            double s = (double)thi[tid][t] + (double)tlo[tid][t];
            double reset = (mem > 1.0) ? 1.0 : 0.0;
            mem = 0.9 * mem + s - reset;
            spk[t] = ((mem - 1.0) > 0.0) ? 1.0f : 0.0f;
        }
        __syncthreads();
        #pragma unroll
        for (int t = 0; t < TC; ++t) thi[tid][t] = spk[t];
        __syncthreads();
        #pragma unroll
        for (int p = 0; p < 4; ++p) {
            int id = tid + p * 256;
            int r = id / 4, c = (id % 4) * 4;
            float4 v = make_float4(thi[r][c], thi[r][c+1], thi[r][c+2], thi[r][c+3]);
            *(float4*)&hi[(row0 + r) * T_DIM + t0 + c] = v;
        }
        __syncthreads();
    }
}

extern "C" void kernel_launch(void* const* d_in, const int* in_sizes, int n_in,
                              void* d_out, int out_size, void* d_ws, size_t ws_size,
                              hipStream_t stream)
{
    const float* x = (const float*)d_in[0];
    const float* W = (const float*)d_in[1];
    float* hi = (float*)d_out;
    char* ws = (char*)d_ws;
    float* lo = (float*)(ws + LO_OFF);

    if (ws_size >= WS_NEED) {
        signed char* wsl = (signed char*)(ws + WSL_OFF);
        signed char* xsl = (signed char*)(ws + XSL_OFF);
        int* alpha = (int*)(ws + AL_OFF);
        int* beta  = (int*)(ws + BE_OFF);
        float* part = (float*)(ws + PART_OFF);

        k_beta_part<<<dim3(16, B_DIM), dim3(256), 0, stream>>>(x, part);
        k_beta<<<dim3(B_DIM), dim3(256), 0, stream>>>(part, beta);
        k_slice_w<<<dim3(OUT_DIM), dim3(256), 0, stream>>>(W, wsl, alpha);
        k_slice_x<<<dim3(4, 16, B_DIM), dim3(256), 0, stream>>>(x, beta, xsl);
        k_oz_gemm<<<dim3(4, 16, B_DIM), dim3(256), 0, stream>>>(wsl, xsl, alpha, beta, hi, lo);
    } else {
        spk_gemm_mfma64p_kernel<<<dim3(2, 8, B_DIM), dim3(256), 0, stream>>>(x, W, hi, lo);
    }
    spk_scan_f64_kernel<<<dim3((B_DIM * OUT_DIM) / 256), dim3(256), 0, stream>>>(hi, lo);
}

// Round 2
// 471.929 us; speedup vs baseline: 1.0673x; 1.0364x over previous
//
#include <hip/hip_runtime.h>

// B=64, IN=1024, OUT=1024, T=256
// syn[b,o,t] = sum_i W[o,i]*x[b,i,t]; spikes via f64 LIF scan.
//
// R12: LDS-bandwidth fix. R11 sat exactly on the LDS roofline of the 64x64
// block (per-CU-step: 336 MFMA cyc/SIMD vs 562 LDS cyc -> 59.8% ceiling,
// observed 58.0%). New geometry: 128x128 block, 8 waves (512 thr), per-wave
// tile 32(o)x64(t): 18 frag-reads / 42 MFMAs per wave-step (0.43 KB/MFMA vs
// 0.57) and 48KB staging per 336 block-MFMAs. New ceiling ~90% MfmaUtil.
// Pipeline unchanged from R11: triple buffer (3x48KB=144KB LDS, 1 block/CU,
// 2 waves/SIMD), depth-2 prefetch, counted s_waitcnt vmcnt(6), setprio(1)
// around MFMA cluster. acc = 12x v16i (192 AGPR) + ~50 arch VGPR <= 256.
// Numerics identical (6 digits, p+q<=5, proven R9). Fragment-ordered wsl/xsl
// (R8: zero bank conflicts), DMA dest = wave-uniform base + lane*16.
// D-placement decoded by runtime probes. Fallback: R6 f64-MFMA path.

#define B_DIM 64
#define IN_DIM 1024
#define OUT_DIM 1024
#define T_DIM 256

typedef int v4i __attribute__((ext_vector_type(4)));
typedef int v16i __attribute__((ext_vector_type(16)));
typedef double v4d __attribute__((ext_vector_type(4)));

// ---------------- workspace layout (bytes) ----------------
#define LO_OFF   0ull                    // 67108864  f32 syn_lo
#define WSL_OFF  67108864ull             // 6291456   i8 W frags [6][o32:32][ks:32][lane:64][16]
#define XSL_OFF  73400320ull             // 100663296 i8 x frags [6][b:64][t32:8][ks:32][lane:64][16]
#define AL_OFF   174063616ull            // 4096      i32 alpha_e[1024]
#define BE_OFF   174067712ull            // 65536     i32 beta_e[64][256]
#define PART_OFF 174133248ull            // 1048576   f32 partial maxes [64][16][256]
#define WS_NEED  175181824ull

__device__ __forceinline__ void gload_lds16(const void* g, void* l)
{
    __builtin_amdgcn_global_load_lds(
        (const __attribute__((address_space(1))) void*)g,
        (__attribute__((address_space(3))) void*)l, 16, 0, 0);
}

// ---------------- K1a: partial column maxes (proven) ----------------
__global__ __launch_bounds__(256) void k_beta_part(const float* __restrict__ x,
                                                   float* __restrict__ part)
{
    const int ic = blockIdx.x;   // i chunk 0..15
    const int b  = blockIdx.y;
    const int t  = threadIdx.x;
    const float* p = x + ((size_t)b * IN_DIM + ic * 64) * T_DIM + t;
    float m = 0.f;
    #pragma unroll 4
    for (int i = 0; i < 64; ++i) m = fmaxf(m, fabsf(p[(size_t)i * T_DIM]));
    part[((size_t)b * 16 + ic) * T_DIM + t] = m;
}

// ---------------- K1b: beta exponents (proven) ----------------
__global__ __launch_bounds__(256) void k_beta(const float* __restrict__ part,
                                              int* __restrict__ beta_e)
{
    const int b = blockIdx.x, t = threadIdx.x;
    float m = 0.f;
    #pragma unroll
    for (int ic = 0; ic < 16; ++ic)
        m = fmaxf(m, part[((size_t)b * 16 + ic) * T_DIM + t]);
    int e = 0;
    if (m > 0.f) frexpf(m, &e);   // |x|/2^e < 1
    beta_e[b * T_DIM + t] = e;
}

// ---------------- K2: slice x -> fragment order (proven R8) ----------------
__global__ __launch_bounds__(256) void k_slice_x(const float* __restrict__ x,
    const int* __restrict__ beta_e, signed char* __restrict__ xsl)
{
    __shared__ float ft[64][65];
    const int tb = blockIdx.x;    // 0..3
    const int ib = blockIdx.y;    // 0..15
    const int b  = blockIdx.z;
    const int tid = threadIdx.x;
    const int t0 = tb * 64, i0 = ib * 64;
    #pragma unroll
    for (int p = 0; p < 16; ++p) {
        int id = tid + p * 256;
        int il = id >> 6, tl = id & 63;
        ft[il][tl] = x[((size_t)b * IN_DIM + i0 + il) * T_DIM + t0 + tl];
    }
    __syncthreads();

    const int t32l = tid >> 7;
    const int ksl  = (tid >> 6) & 1;
    const int lane = tid & 63;
    const int t_local = t32l * 32 + (lane & 31);
    const int k_local = ksl * 32 + (lane >> 5) * 16;
    const int e = beta_e[b * T_DIM + t0 + t_local];

    signed char dig[16][6];
    #pragma unroll
    for (int j = 0; j < 16; ++j) {
        double r = ldexp((double)ft[k_local + j][t_local], -e);  // exact dyadic
        #pragma unroll
        for (int p = 0; p < 6; ++p) {
            r *= 128.0;              // exact
            double d = trunc(r);     // digit in [-127,127]
            r -= d;                  // exact
            dig[j][p] = (signed char)(int)d;
        }
    }
    #pragma unroll
    for (int p = 0; p < 6; ++p) {
        int w[4];
        #pragma unroll
        for (int g = 0; g < 4; ++g)
            w[g] = (dig[4*g][p] & 0xff) | ((dig[4*g+1][p] & 0xff) << 8) |
                   ((dig[4*g+2][p] & 0xff) << 16) | ((dig[4*g+3][p] & 0xff) << 24);
        const size_t base =
            ((((size_t)p * B_DIM + b) * 8 + (tb * 2 + t32l)) * 32 + (ib * 2 + ksl)) * 1024
            + lane * 16;
        *(v4i*)&xsl[base] = (v4i){w[0], w[1], w[2], w[3]};
    }
}

// ---------------- K3: alpha + slice W -> fragment order (proven R8) --------
__global__ __launch_bounds__(256) void k_slice_w(const float* __restrict__ W,
    signed char* __restrict__ wsl, int* __restrict__ alpha_e)
{
    __shared__ float red[256];
    __shared__ float wrow[1024];
    __shared__ int se;
    const int o = blockIdx.x, tid = threadIdx.x;
    float4 v = *(const float4*)&W[(size_t)o * IN_DIM + tid * 4];
    *(float4*)&wrow[tid * 4] = v;
    float m = fmaxf(fmaxf(fabsf(v.x), fabsf(v.y)), fmaxf(fabsf(v.z), fabsf(v.w)));
    red[tid] = m; __syncthreads();
    for (int s = 128; s > 0; s >>= 1) {
        if (tid < s) red[tid] = fmaxf(red[tid], red[tid + s]);
        __syncthreads();
    }
    if (tid == 0) { int e = 0; if (red[0] > 0.f) frexpf(red[0], &e); se = e; alpha_e[o] = e; }
    __syncthreads();
    if (tid >= 64) return;
    const int e = se;
    const int ks = tid >> 1, khalf = tid & 1;
    const int k0 = tid * 16;
    const int lane = (o & 31) + 32 * khalf;

    signed char dig[16][6];
    #pragma unroll
    for (int j = 0; j < 16; ++j) {
        double r = ldexp((double)wrow[k0 + j], -e);
        #pragma unroll
        for (int p = 0; p < 6; ++p) {
            r *= 128.0; double d = trunc(r); r -= d;
            dig[j][p] = (signed char)(int)d;
        }
    }
    #pragma unroll
    for (int p = 0; p < 6; ++p) {
        int w[4];
        #pragma unroll
        for (int g = 0; g < 4; ++g)
            w[g] = (dig[4*g][p] & 0xff) | ((dig[4*g+1][p] & 0xff) << 8) |
                   ((dig[4*g+2][p] & 0xff) << 16) | ((dig[4*g+3][p] & 0xff) << 24);
        const size_t base =
            (((size_t)p * 32 + (o >> 5)) * 32 + ks) * 1024 + lane * 16;
        *(v4i*)&wsl[base] = (v4i){w[0], w[1], w[2], w[3]};
    }
}

// ---------------- K4: Ozaki i8 MFMA GEMM, 128x128 block ----------------
// 8 waves (512 thr), wave tile 32(o)x64(t): woh=wave>>1 (o sub 0..3),
// wth=wave&1 (t half). Per k-step per wave: 6 af + 12 bf reads, 42 MFMAs.
// LDS buffer (48KB): A [p:6][sub:4][1024] at 0, B [q:6][sub:4][1024] at 24576.
// Staging: wave w issue j (j=0..5): j<3 -> A frag f=w+8j (p=(w>>2)+2j,
// sub=w&3); j>=3 -> B frag g=w+8(j-3) (q=(w>>2)+2(j-3), sub=w&3).
// 6 gload_lds16/thread/step; depth-2 triple buffer; steady-state 12
// outstanding -> s_waitcnt vmcnt(6) retires the oldest tile while the newest
// stays in flight ACROSS the raw s_barrier. Writes: step kt fills
// LB[(kt+2)%3], reads LB[kt%3]; overwritten buffer's last read was at kt-1,
// barrier-separated from this issue.
#define OZ_LOADS(PF)                                                        \
    {                                                                       \
        _Pragma("unroll")                                                   \
        for (int j = 0; j < 3; ++j) {                                       \
            gload_lds16(aBase + ((size_t)j << 21), &LB[PF][ldsA + j * 8192]); \
            gload_lds16(bBase + ((size_t)j << 25), &LB[PF][ldsB + j * 8192]); \
        }                                                                   \
        aBase += 1024; bBase += 1024;                                       \
    }

#define OZ_MATH(CUR)                                                        \
    {                                                                       \
        const signed char* base_ = LB[CUR];                                 \
        v4i af[6];                                                          \
        _Pragma("unroll")                                                   \
        for (int p = 0; p < 6; ++p)                                         \
            af[p] = *(const v4i*)(base_ + p * 4096 + aoffm);                \
        __builtin_amdgcn_s_setprio(1);                                      \
        _Pragma("unroll")                                                   \
        for (int q = 0; q < 6; ++q) {                                       \
            v4i b0 = *(const v4i*)(base_ + 24576 + q * 4096 + boffm);       \
            v4i b1 = *(const v4i*)(base_ + 24576 + q * 4096 + boffm + 1024);\
            _Pragma("unroll")                                               \
            for (int p = 0; p + q < 6; ++p) {                               \
                accA[p + q] = __builtin_amdgcn_mfma_i32_32x32x32_i8(        \
                    af[p], b0, accA[p + q], 0, 0, 0);                       \
                accB[p + q] = __builtin_amdgcn_mfma_i32_32x32x32_i8(        \
                    af[p], b1, accB[p + q], 0, 0, 0);                       \
            }                                                               \
        }                                                                   \
        __builtin_amdgcn_s_setprio(0);                                      \
    }

#define VMBAR(N)                                                            \
    do {                                                                    \
        asm volatile("s_waitcnt vmcnt(" #N ")" ::: "memory");               \
        __builtin_amdgcn_s_barrier();                                       \
    } while (0)

__global__ __launch_bounds__(512, 2) void k_oz_gemm(
    const signed char* __restrict__ wsl, const signed char* __restrict__ xsl,
    const int* __restrict__ alpha_e, const int* __restrict__ beta_e,
    float* __restrict__ syn_hi, float* __restrict__ syn_lo)
{
    __shared__ __align__(16) signed char LB[3][49152];

    const int tid = threadIdx.x;
    const int lane = tid & 63, wave = tid >> 6;    // wave 0..7
    const int tb = blockIdx.x;   // 0..1 (t block of 128)
    const int ob = blockIdx.y;   // 0..7 (o block of 128)
    const int b  = blockIdx.z;
    const int o0 = ob * 128, t0 = tb * 128;
    const int woh = wave >> 1;   // o sub 0..3 (32 rows each)
    const int wth = wave & 1;    // t half 0..1 (64 cols each)
    const int l16 = lane * 16;

    v16i accA[6], accB[6];
    #pragma unroll
    for (int s = 0; s < 6; ++s) {
        accA[s] = (v16i){0,0,0,0,0,0,0,0,0,0,0,0,0,0,0,0};
        accB[s] = (v16i){0,0,0,0,0,0,0,0,0,0,0,0,0,0,0,0};
    }

    // Staging bases (per wave): A frag f=w+8j at p=(w>>2)+2j, sub=w&3.
    // wsl addr = (p<<20) + (o32<<15) + (kt<<10) + lane*16, o32 = 4*ob+sub.
    // xsl addr = (q<<24) + (b<<18) + (t32<<15) + (kt<<10) + lane*16.
    const signed char* aBase = wsl + ((size_t)(wave >> 2) << 20)
                                   + ((size_t)(4 * ob + (wave & 3)) << 15) + l16;
    const signed char* bBase = xsl + ((size_t)(wave >> 2) << 24)
                                   + ((size_t)b << 18)
                                   + ((size_t)(4 * tb + (wave & 3)) << 15) + l16;
    const int ldsA = wave * 1024;            // + j*8192 (A region [0,24576))
    const int ldsB = 24576 + wave * 1024;    // + j*8192 (B region)

    // Math-side LDS offsets (fragment reads).
    const int aoffm = woh * 1024 + l16;          // + p*4096
    const int boffm = wth * 2048 + l16;          // + q*4096 (+1024 for 2nd sub)

    // prologue: kt=0 -> LB[0], kt=1 -> LB[1]; retire kt=0 (vmcnt 12->6).
    OZ_LOADS(0)
    OZ_LOADS(1)
    VMBAR(6);

    // steady state: kt = 0..29, buffers rotate (0,1,2). Never drain to 0.
    #pragma unroll 1
    for (int it = 0; it < 10; ++it) {
        OZ_LOADS(2) OZ_MATH(0) VMBAR(6);
        OZ_LOADS(0) OZ_MATH(1) VMBAR(6);
        OZ_LOADS(1) OZ_MATH(2) VMBAR(6);
    }
    // kt=30: nothing left to issue; drain kt=31's 6 loads, last barrier.
    OZ_MATH(0) VMBAR(0);
    // kt=31: registers only from here on.
    OZ_MATH(1)

    // Runtime D-placement probes (R6/R7 technique).
    const int lr = lane & 31;
    const int rv = (lr + 1) * 0x01010101;
    const v4i pav  = {rv, rv, rv, rv};
    const v4i onev = {0x01010101, 0x01010101, 0x01010101, 0x01010101};
    const v16i z = (v16i){0,0,0,0,0,0,0,0,0,0,0,0,0,0,0,0};
    v16i d1 = __builtin_amdgcn_mfma_i32_32x32x32_i8(pav, onev, z, 0, 0, 0);
    v16i d2 = __builtin_amdgcn_mfma_i32_32x32x32_i8(onev, pav, z, 0, 0, 0);

    const int col = (d2[0] >> 5) - 1;            // 0..31 within tile
    const int gtA = t0 + wth * 64 + col;         // t32 sub 2*wth
    const int gtB = gtA + 32;                    // t32 sub 2*wth+1
    const int ebA = beta_e[b * T_DIM + gtA];
    const int ebB = beta_e[b * T_DIM + gtB];
    float* ohiA = syn_hi + ((size_t)b * OUT_DIM + o0) * T_DIM + gtA;
    float* oloA = syn_lo + ((size_t)b * OUT_DIM + o0) * T_DIM + gtA;

    const double C0 = 0x1p-14, C1 = 0x1p-21, C2 = 0x1p-28, C3 = 0x1p-35,
                 C4 = 0x1p-42, C5 = 0x1p-49;
    #pragma unroll
    for (int r = 0; r < 16; ++r) {
        const int row = (d1[r] >> 5) - 1;        // 0..31 within tile
        const int go = woh * 32 + row;
        const int ea = alpha_e[o0 + go];
        double vA = (double)accA[0][r] * C0 + (double)accA[1][r] * C1 +
                    (double)accA[2][r] * C2 + (double)accA[3][r] * C3 +
                    (double)accA[4][r] * C4 + (double)accA[5][r] * C5;
        double vB = (double)accB[0][r] * C0 + (double)accB[1][r] * C1 +
                    (double)accB[2][r] * C2 + (double)accB[3][r] * C3 +
                    (double)accB[4][r] * C4 + (double)accB[5][r] * C5;
        double synA = ldexp(vA, ea + ebA);
        double synB = ldexp(vB, ea + ebB);
        float hiA = (float)synA;
        float loA = (float)(synA - (double)hiA);
        float hiB = (float)synB;
        float loB = (float)(synB - (double)hiB);
        const size_t off = (size_t)go * T_DIM;
        ohiA[off] = hiA;       oloA[off] = loA;
        ohiA[off + 32] = hiB;  oloA[off + 32] = loB;
    }
}

// ---------------- Fallback GEMM: R6 f64-MFMA with probes (proven) ----------
#define BM 128
#define BN 128
#define BK 16
#define LDA 130

__global__ __launch_bounds__(256, 2) void spk_gemm_mfma64p_kernel(
    const float* __restrict__ x, const float* __restrict__ W,
    float* __restrict__ syn_hi, float* __restrict__ syn_lo)
{
    const int tid  = threadIdx.x;
    const int lane = tid & 63;
    const int wave = tid >> 6;
    const int tb = blockIdx.x, ob = blockIdx.y, b = blockIdx.z;

    __shared__ __align__(16) double As[BK][LDA];
    __shared__ __align__(16) double Bs[BK][LDA];

    const v4d zz = {0.0, 0.0, 0.0, 0.0};
    v4d d1 = __builtin_amdgcn_mfma_f64_16x16x4f64((double)lane, 1.0, zz, 0, 0, 0);
    v4d d2 = __builtin_amdgcn_mfma_f64_16x16x4f64(1.0, (double)lane, zz, 0, 0, 0);
    const bool a_h1 = (((int)d1[0] & 3) == 0);
    const bool b_h1 = (((int)d2[0] & 3) == 0);
    int drow[4];
    #pragma unroll
    for (int r = 0; r < 4; ++r) {
        const int v = (int)d1[r];
        drow[r] = (a_h1 ? (v - 96) >> 2 : (v - 6) >> 4) & 15;
    }
    const int am = a_h1 ? (lane & 15) : (lane >> 2);
    const int ak = a_h1 ? (lane >> 4) : (lane & 3);
    const int bn = b_h1 ? (lane & 15) : (lane >> 2);
    const int bk = b_h1 ? (lane >> 4) : (lane & 3);
    const int dcol = lane & 15;

    const int o0 = ob * BM, t0 = tb * BN;
    const float* Wp = W + (size_t)o0 * IN_DIM;
    const float* xp = x + (size_t)b * IN_DIM * T_DIM + t0;
    const int wo = (wave >> 1) * 64, wt = (wave & 1) * 64;

    v4d acc[4][4];
    #pragma unroll
    for (int i = 0; i < 4; ++i)
        #pragma unroll
        for (int j = 0; j < 4; ++j) acc[i][j] = zz;

    const int ar0 = tid / 4, ac = (tid % 4) * 4;
    const int bkr0 = tid / 32, btc = (tid % 32) * 4;

    float4 pa[2], pb[2];
    #pragma unroll
    for (int p = 0; p < 2; ++p) {
        pa[p] = *(const float4*)&Wp[(size_t)(ar0 + p * 64) * IN_DIM + ac];
        pb[p] = *(const float4*)&xp[(size_t)(bkr0 + p * 8) * T_DIM + btc];
    }

    for (int k0 = 0; k0 < IN_DIM; k0 += BK) {
        #pragma unroll
        for (int p = 0; p < 2; ++p) {
            const int r = ar0 + p * 64;
            As[ac + 0][r] = (double)pa[p].x; As[ac + 1][r] = (double)pa[p].y;
            As[ac + 2][r] = (double)pa[p].z; As[ac + 3][r] = (double)pa[p].w;
            const int kr = bkr0 + p * 8;
            Bs[kr][btc + 0] = (double)pb[p].x; Bs[kr][btc + 1] = (double)pb[p].y;
            Bs[kr][btc + 2] = (double)pb[p].z; Bs[kr][btc + 3] = (double)pb[p].w;
        }
        if (k0 + BK < IN_DIM) {
            #pragma unroll
            for (int p = 0; p < 2; ++p) {
                pa[p] = *(const float4*)&Wp[(size_t)(ar0 + p * 64) * IN_DIM + k0 + BK + ac];
                pb[p] = *(const float4*)&xp[(size_t)(bkr0 + p * 8 + k0 + BK) * T_DIM + btc];
            }
        }
        __syncthreads();
        #pragma unroll
        for (int kk = 0; kk < 4; ++kk) {
            const int kra = kk * 4 + ak, krb = kk * 4 + bk;
            double a[4], bb[4];
            #pragma unroll
            for (int i = 0; i < 4; ++i) a[i] = As[kra][wo + i * 16 + am];
            #pragma unroll
            for (int j = 0; j < 4; ++j) bb[j] = Bs[krb][wt + j * 16 + bn];
            #pragma unroll
            for (int i = 0; i < 4; ++i)
                #pragma unroll
                for (int j = 0; j < 4; ++j)
                    acc[i][j] = __builtin_amdgcn_mfma_f64_16x16x4f64(a[i], bb[j], acc[i][j], 0, 0, 0);
        }
        __syncthreads();
    }

    float* ohi = syn_hi + ((size_t)b * OUT_DIM + o0) * T_DIM + t0;
    float* olo = syn_lo + ((size_t)b * OUT_DIM + o0) * T_DIM + t0;
    #pragma unroll
    for (int i = 0; i < 4; ++i)
        #pragma unroll
        for (int j = 0; j < 4; ++j) {
            const int col = wt + j * 16 + dcol;
            #pragma unroll
            for (int r = 0; r < 4; ++r) {
                double s = acc[i][j][r];
                float hi = (float)s;
                float lo = (float)(s - (double)hi);
                const size_t off = (size_t)(wo + i * 16 + drow[r]) * T_DIM + col;
                ohi[off] = hi; olo[off] = lo;
            }
        }
}

// ---------------- scan: f64 LIF, in place over hi (proven) ----------------
__global__ __launch_bounds__(256) void spk_scan_f64_kernel(
    float* __restrict__ hi, const float* __restrict__ lo)
{
    const int TC = 16;
    __shared__ float thi[256][TC + 1];
    __shared__ float tlo[256][TC + 1];
    const int tid = threadIdx.x;
    const size_t row0 = (size_t)blockIdx.x * 256;

    double mem = 0.0;
    for (int t0 = 0; t0 < T_DIM; t0 += TC) {
        #pragma unroll
        for (int p = 0; p < 4; ++p) {
            int id = tid + p * 256;
            int r = id / 4, c = (id % 4) * 4;
            size_t g = (row0 + r) * T_DIM + t0 + c;
            float4 vh = *(const float4*)&hi[g];
            thi[r][c] = vh.x; thi[r][c+1] = vh.y; thi[r][c+2] = vh.z; thi[r][c+3] = vh.w;
            float4 vl = *(const float4*)&lo[g];
            tlo[r][c] = vl.x; tlo[r][c+1] = vl.y; tlo[r][c+2] = vl.z; tlo[r][c+3] = vl.w;
        }
        __syncthreads();
        float spk[TC];
        #pragma unroll
        for (int t = 0; t < TC; ++t) {
            double s = (double)thi[tid][t] + (double)tlo[tid][t];
            double reset = (mem > 1.0) ? 1.0 : 0.0;
            mem = 0.9 * mem + s - reset;
            spk[t] = ((mem - 1.0) > 0.0) ? 1.0f : 0.0f;
        }
        __syncthreads();
        #pragma unroll
        for (int t = 0; t < TC; ++t) thi[tid][t] = spk[t];
        __syncthreads();
        #pragma unroll
        for (int p = 0; p < 4; ++p) {
            int id = tid + p * 256;
            int r = id / 4, c = (id % 4) * 4;
            float4 v = make_float4(thi[r][c], thi[r][c+1], thi[r][c+2], thi[r][c+3]);
            *(float4*)&hi[(row0 + r) * T_DIM + t0 + c] = v;
        }
        __syncthreads();
    }
}

extern "C" void kernel_launch(void* const* d_in, const int* in_sizes, int n_in,
                              void* d_out, int out_size, void* d_ws, size_t ws_size,
                              hipStream_t stream)
{
    const float* x = (const float*)d_in[0];
    const float* W = (const float*)d_in[1];
    float* hi = (float*)d_out;
    char* ws = (char*)d_ws;
    float* lo = (float*)(ws + LO_OFF);

    if (ws_size >= WS_NEED) {
        signed char* wsl = (signed char*)(ws + WSL_OFF);
        signed char* xsl = (signed char*)(ws + XSL_OFF);
        int* alpha = (int*)(ws + AL_OFF);
        int* beta  = (int*)(ws + BE_OFF);
        float* part = (float*)(ws + PART_OFF);

        k_beta_part<<<dim3(16, B_DIM), dim3(256), 0, stream>>>(x, part);
        k_beta<<<dim3(B_DIM), dim3(256), 0, stream>>>(part, beta);
        k_slice_w<<<dim3(OUT_DIM), dim3(256), 0, stream>>>(W, wsl, alpha);
        k_slice_x<<<dim3(4, 16, B_DIM), dim3(256), 0, stream>>>(x, beta, xsl);
        k_oz_gemm<<<dim3(2, 8, B_DIM), dim3(512), 0, stream>>>(wsl, xsl, alpha, beta, hi, lo);
    } else {
        spk_gemm_mfma64p_kernel<<<dim3(2, 8, B_DIM), dim3(256), 0, stream>>>(x, W, hi, lo);
    }
    spk_scan_f64_kernel<<<dim3((B_DIM * OUT_DIM) / 256), dim3(256), 0, stream>>>(hi, lo);
}

// Round 4
// 396.473 us; speedup vs baseline: 1.2704x; 1.1903x over previous
//
#include <hip/hip_runtime.h>

// B=64, IN=1024, OUT=1024, T=256
// syn[b,o,t] = sum_i W[o,i]*x[b,i,t]; spikes via f64 LIF scan.
//
// R14 = R13 resubmit (R13 bench died to container infra, no kernel verdict).
// 5-digit Ozaki (p+q<=4 -> 15 pairs, 30 MFMAs/wave-step). Error budget:
// dropped terms ~1e-9 abs on syn vs the jax f32 reference's own ~5e-7 error
// margin (dataset-proven at R9). Cuts MFMA floor 164->117 us AND LDS reads
// 144->120 KB/step (the two measured serial components: exposed time ~=
// LDS-read-bytes / 85 B/cyc, calibrated on R11+R12).
// Geometry from R12: 128x128 block, 8 waves, wave tile 32(o)x64(t).
// Pipeline from R11: triple buffer (3x40KB=120KB LDS), depth-2 prefetch,
// counted s_waitcnt vmcnt(5) (5 gload_lds16/thread/step, 40 segments),
// setprio(1) around MFMA cluster. acc = 10x v16i (160 AGPR).
// Fragment-ordered wsl/xsl (R8: zero bank conflicts), DMA dest =
// wave-uniform base + lane*16. D-placement by runtime probes.
// Fallback: R6 f64-MFMA path.

#define B_DIM 64
#define IN_DIM 1024
#define OUT_DIM 1024
#define T_DIM 256

typedef int v4i __attribute__((ext_vector_type(4)));
typedef int v16i __attribute__((ext_vector_type(16)));
typedef double v4d __attribute__((ext_vector_type(4)));

// ---------------- workspace layout (bytes) ----------------
#define LO_OFF   0ull                    // 67108864  f32 syn_lo
#define WSL_OFF  67108864ull             // 6291456   i8 W frags [p:5][o32:32][ks:32][lane:64][16]
#define XSL_OFF  73400320ull             // 100663296 i8 x frags [q:5][b:64][t32:8][ks:32][lane:64][16]
#define AL_OFF   174063616ull            // 4096      i32 alpha_e[1024]
#define BE_OFF   174067712ull            // 65536     i32 beta_e[64][256]
#define PART_OFF 174133248ull            // 1048576   f32 partial maxes [64][16][256]
#define WS_NEED  175181824ull

__device__ __forceinline__ void gload_lds16(const void* g, void* l)
{
    __builtin_amdgcn_global_load_lds(
        (const __attribute__((address_space(1))) void*)g,
        (__attribute__((address_space(3))) void*)l, 16, 0, 0);
}

// ---------------- K1a: partial column maxes (proven) ----------------
__global__ __launch_bounds__(256) void k_beta_part(const float* __restrict__ x,
                                                   float* __restrict__ part)
{
    const int ic = blockIdx.x;   // i chunk 0..15
    const int b  = blockIdx.y;
    const int t  = threadIdx.x;
    const float* p = x + ((size_t)b * IN_DIM + ic * 64) * T_DIM + t;
    float m = 0.f;
    #pragma unroll 4
    for (int i = 0; i < 64; ++i) m = fmaxf(m, fabsf(p[(size_t)i * T_DIM]));
    part[((size_t)b * 16 + ic) * T_DIM + t] = m;
}

// ---------------- K1b: beta exponents (proven) ----------------
__global__ __launch_bounds__(256) void k_beta(const float* __restrict__ part,
                                              int* __restrict__ beta_e)
{
    const int b = blockIdx.x, t = threadIdx.x;
    float m = 0.f;
    #pragma unroll
    for (int ic = 0; ic < 16; ++ic)
        m = fmaxf(m, part[((size_t)b * 16 + ic) * T_DIM + t]);
    int e = 0;
    if (m > 0.f) frexpf(m, &e);   // |x|/2^e < 1
    beta_e[b * T_DIM + t] = e;
}

// ---------------- K2: slice x -> fragment order (5 digits) ----------------
__global__ __launch_bounds__(256) void k_slice_x(const float* __restrict__ x,
    const int* __restrict__ beta_e, signed char* __restrict__ xsl)
{
    __shared__ float ft[64][65];
    const int tb = blockIdx.x;    // 0..3
    const int ib = blockIdx.y;    // 0..15
    const int b  = blockIdx.z;
    const int tid = threadIdx.x;
    const int t0 = tb * 64, i0 = ib * 64;
    #pragma unroll
    for (int p = 0; p < 16; ++p) {
        int id = tid + p * 256;
        int il = id >> 6, tl = id & 63;
        ft[il][tl] = x[((size_t)b * IN_DIM + i0 + il) * T_DIM + t0 + tl];
    }
    __syncthreads();

    const int t32l = tid >> 7;
    const int ksl  = (tid >> 6) & 1;
    const int lane = tid & 63;
    const int t_local = t32l * 32 + (lane & 31);
    const int k_local = ksl * 32 + (lane >> 5) * 16;
    const int e = beta_e[b * T_DIM + t0 + t_local];

    signed char dig[16][5];
    #pragma unroll
    for (int j = 0; j < 16; ++j) {
        double r = ldexp((double)ft[k_local + j][t_local], -e);  // exact dyadic
        #pragma unroll
        for (int p = 0; p < 5; ++p) {
            r *= 128.0;              // exact
            double d = trunc(r);     // digit in [-127,127]
            r -= d;                  // exact
            dig[j][p] = (signed char)(int)d;
        }
    }
    #pragma unroll
    for (int p = 0; p < 5; ++p) {
        int w[4];
        #pragma unroll
        for (int g = 0; g < 4; ++g)
            w[g] = (dig[4*g][p] & 0xff) | ((dig[4*g+1][p] & 0xff) << 8) |
                   ((dig[4*g+2][p] & 0xff) << 16) | ((dig[4*g+3][p] & 0xff) << 24);
        const size_t base =
            ((((size_t)p * B_DIM + b) * 8 + (tb * 2 + t32l)) * 32 + (ib * 2 + ksl)) * 1024
            + lane * 16;
        *(v4i*)&xsl[base] = (v4i){w[0], w[1], w[2], w[3]};
    }
}

// ---------------- K3: alpha + slice W (5 digits) --------
__global__ __launch_bounds__(256) void k_slice_w(const float* __restrict__ W,
    signed char* __restrict__ wsl, int* __restrict__ alpha_e)
{
    __shared__ float red[256];
    __shared__ float wrow[1024];
    __shared__ int se;
    const int o = blockIdx.x, tid = threadIdx.x;
    float4 v = *(const float4*)&W[(size_t)o * IN_DIM + tid * 4];
    *(float4*)&wrow[tid * 4] = v;
    float m = fmaxf(fmaxf(fabsf(v.x), fabsf(v.y)), fmaxf(fabsf(v.z), fabsf(v.w)));
    red[tid] = m; __syncthreads();
    for (int s = 128; s > 0; s >>= 1) {
        if (tid < s) red[tid] = fmaxf(red[tid], red[tid + s]);
        __syncthreads();
    }
    if (tid == 0) { int e = 0; if (red[0] > 0.f) frexpf(red[0], &e); se = e; alpha_e[o] = e; }
    __syncthreads();
    if (tid >= 64) return;
    const int e = se;
    const int ks = tid >> 1, khalf = tid & 1;
    const int k0 = tid * 16;
    const int lane = (o & 31) + 32 * khalf;

    signed char dig[16][5];
    #pragma unroll
    for (int j = 0; j < 16; ++j) {
        double r = ldexp((double)wrow[k0 + j], -e);
        #pragma unroll
        for (int p = 0; p < 5; ++p) {
            r *= 128.0; double d = trunc(r); r -= d;
            dig[j][p] = (signed char)(int)d;
        }
    }
    #pragma unroll
    for (int p = 0; p < 5; ++p) {
        int w[4];
        #pragma unroll
        for (int g = 0; g < 4; ++g)
            w[g] = (dig[4*g][p] & 0xff) | ((dig[4*g+1][p] & 0xff) << 8) |
                   ((dig[4*g+2][p] & 0xff) << 16) | ((dig[4*g+3][p] & 0xff) << 24);
        const size_t base =
            (((size_t)p * 32 + (o >> 5)) * 32 + ks) * 1024 + lane * 16;
        *(v4i*)&wsl[base] = (v4i){w[0], w[1], w[2], w[3]};
    }
}

// ---------------- K4: Ozaki i8 MFMA GEMM, 128x128, 5 digits ----------------
// 8 waves (512 thr), wave tile 32(o)x64(t). Per k-step per wave: 5 af + 10 bf
// LDS reads, 30 MFMAs. LDS buffer (40KB): 40 segments of 1KB; segment
// s = 8j + wave (j=0..4 per-thread loads). s<20 -> A digit p=s>>2, sub=s&3;
// s>=20 -> B digit q=(s-20)>>2, sub=(s-20)&3. Math: A frag at p*4096 +
// woh*1024; B frag at 20480 + q*4096 + (2*wth+{0,1})*1024.
// Depth-2 triple buffer; steady-state 10 outstanding -> s_waitcnt vmcnt(5)
// retires the oldest tile while the newest stays in flight across s_barrier.
#define OZ_LOADS(PF)                                                        \
    {                                                                       \
        _Pragma("unroll")                                                   \
        for (int j = 0; j < 5; ++j) {                                       \
            gload_lds16(gp[j], &LB[PF][lbase + j * 8192]);                  \
            gp[j] += 1024;                                                  \
        }                                                                   \
    }

#define OZ_MATH(CUR)                                                        \
    {                                                                       \
        const signed char* base_ = LB[CUR];                                 \
        v4i af[5];                                                          \
        _Pragma("unroll")                                                   \
        for (int p = 0; p < 5; ++p)                                         \
            af[p] = *(const v4i*)(base_ + p * 4096 + aoffm);                \
        __builtin_amdgcn_s_setprio(1);                                      \
        _Pragma("unroll")                                                   \
        for (int q = 0; q < 5; ++q) {                                       \
            v4i b0 = *(const v4i*)(base_ + 20480 + q * 4096 + boffm);       \
            v4i b1 = *(const v4i*)(base_ + 20480 + q * 4096 + boffm + 1024);\
            _Pragma("unroll")                                               \
            for (int p = 0; p + q < 5; ++p) {                               \
                accA[p + q] = __builtin_amdgcn_mfma_i32_32x32x32_i8(        \
                    af[p], b0, accA[p + q], 0, 0, 0);                       \
                accB[p + q] = __builtin_amdgcn_mfma_i32_32x32x32_i8(        \
                    af[p], b1, accB[p + q], 0, 0, 0);                       \
            }                                                               \
        }                                                                   \
        __builtin_amdgcn_s_setprio(0);                                      \
    }

#define VMBAR(N)                                                            \
    do {                                                                    \
        asm volatile("s_waitcnt vmcnt(" #N ")" ::: "memory");               \
        __builtin_amdgcn_s_barrier();                                       \
    } while (0)

__global__ __launch_bounds__(512, 2) void k_oz_gemm(
    const signed char* __restrict__ wsl, const signed char* __restrict__ xsl,
    const int* __restrict__ alpha_e, const int* __restrict__ beta_e,
    float* __restrict__ syn_hi, float* __restrict__ syn_lo)
{
    __shared__ __align__(16) signed char LB[3][40960];

    const int tid = threadIdx.x;
    const int lane = tid & 63, wave = tid >> 6;    // wave 0..7
    const int tb = blockIdx.x;   // 0..1 (t block of 128)
    const int ob = blockIdx.y;   // 0..7 (o block of 128)
    const int b  = blockIdx.z;
    const int o0 = ob * 128, t0 = tb * 128;
    const int woh = wave >> 1;   // o sub 0..3 (32 rows each)
    const int wth = wave & 1;    // t half 0..1 (64 cols each)
    const int l16 = lane * 16;

    v16i accA[5], accB[5];
    #pragma unroll
    for (int s = 0; s < 5; ++s) {
        accA[s] = (v16i){0,0,0,0,0,0,0,0,0,0,0,0,0,0,0,0};
        accB[s] = (v16i){0,0,0,0,0,0,0,0,0,0,0,0,0,0,0,0};
    }

    // Staging pointers: segment s = 8j + wave.
    // wsl addr = (p<<20) + (o32<<15) + (kt<<10) + lane*16, o32 = 4*ob+sub.
    // xsl addr = (q<<24) + (b<<18) + (t32<<15) + (kt<<10) + lane*16.
    const signed char* gp[5];
    #pragma unroll
    for (int j = 0; j < 5; ++j) {
        const int s = 8 * j + wave;
        if (s < 20) {
            gp[j] = wsl + ((size_t)(s >> 2) << 20)
                        + ((size_t)(4 * ob + (s & 3)) << 15) + l16;
        } else {
            const int t = s - 20;
            gp[j] = xsl + ((size_t)(t >> 2) << 24) + ((size_t)b << 18)
                        + ((size_t)(4 * tb + (t & 3)) << 15) + l16;
        }
    }
    const int lbase = wave * 1024;   // segment s LDS offset = s*1024 = lbase + j*8192

    // Math-side LDS offsets (fragment reads).
    const int aoffm = woh * 1024 + l16;          // + p*4096          (A region)
    const int boffm = wth * 2048 + l16;          // + 20480 + q*4096  (B region)

    // prologue: kt=0 -> LB[0], kt=1 -> LB[1]; retire kt=0 (vmcnt 10->5).
    OZ_LOADS(0)
    OZ_LOADS(1)
    VMBAR(5);

    // steady state: kt = 0..29, buffers rotate (0,1,2). Never drain to 0.
    #pragma unroll 1
    for (int it = 0; it < 10; ++it) {
        OZ_LOADS(2) OZ_MATH(0) VMBAR(5);
        OZ_LOADS(0) OZ_MATH(1) VMBAR(5);
        OZ_LOADS(1) OZ_MATH(2) VMBAR(5);
    }
    // kt=30: nothing left to issue; drain kt=31's 5 loads, last barrier.
    OZ_MATH(0) VMBAR(0);
    // kt=31: registers only from here on.
    OZ_MATH(1)

    // Runtime D-placement probes (R6/R7 technique).
    const int lr = lane & 31;
    const int rv = (lr + 1) * 0x01010101;
    const v4i pav  = {rv, rv, rv, rv};
    const v4i onev = {0x01010101, 0x01010101, 0x01010101, 0x01010101};
    const v16i z = (v16i){0,0,0,0,0,0,0,0,0,0,0,0,0,0,0,0};
    v16i d1 = __builtin_amdgcn_mfma_i32_32x32x32_i8(pav, onev, z, 0, 0, 0);
    v16i d2 = __builtin_amdgcn_mfma_i32_32x32x32_i8(onev, pav, z, 0, 0, 0);

    const int col = (d2[0] >> 5) - 1;            // 0..31 within tile
    const int gtA = t0 + wth * 64 + col;         // t32 sub 2*wth
    const int gtB = gtA + 32;                    // t32 sub 2*wth+1
    const int ebA = beta_e[b * T_DIM + gtA];
    const int ebB = beta_e[b * T_DIM + gtB];
    float* ohiA = syn_hi + ((size_t)b * OUT_DIM + o0) * T_DIM + gtA;
    float* oloA = syn_lo + ((size_t)b * OUT_DIM + o0) * T_DIM + gtA;

    const double C0 = 0x1p-14, C1 = 0x1p-21, C2 = 0x1p-28, C3 = 0x1p-35,
                 C4 = 0x1p-42;
    #pragma unroll
    for (int r = 0; r < 16; ++r) {
        const int row = (d1[r] >> 5) - 1;        // 0..31 within tile
        const int go = woh * 32 + row;
        const int ea = alpha_e[o0 + go];
        double vA = (double)accA[0][r] * C0 + (double)accA[1][r] * C1 +
                    (double)accA[2][r] * C2 + (double)accA[3][r] * C3 +
                    (double)accA[4][r] * C4;
        double vB = (double)accB[0][r] * C0 + (double)accB[1][r] * C1 +
                    (double)accB[2][r] * C2 + (double)accB[3][r] * C3 +
                    (double)accB[4][r] * C4;
        double synA = ldexp(vA, ea + ebA);
        double synB = ldexp(vB, ea + ebB);
        float hiA = (float)synA;
        float loA = (float)(synA - (double)hiA);
        float hiB = (float)synB;
        float loB = (float)(synB - (double)hiB);
        const size_t off = (size_t)go * T_DIM;
        ohiA[off] = hiA;       oloA[off] = loA;
        ohiA[off + 32] = hiB;  oloA[off + 32] = loB;
    }
}

// ---------------- Fallback GEMM: R6 f64-MFMA with probes (proven) ----------
#define BM 128
#define BN 128
#define BK 16
#define LDA 130

__global__ __launch_bounds__(256, 2) void spk_gemm_mfma64p_kernel(
    const float* __restrict__ x, const float* __restrict__ W,
    float* __restrict__ syn_hi, float* __restrict__ syn_lo)
{
    const int tid  = threadIdx.x;
    const int lane = tid & 63;
    const int wave = tid >> 6;
    const int tb = blockIdx.x, ob = blockIdx.y, b = blockIdx.z;

    __shared__ __align__(16) double As[BK][LDA];
    __shared__ __align__(16) double Bs[BK][LDA];

    const v4d zz = {0.0, 0.0, 0.0, 0.0};
    v4d d1 = __builtin_amdgcn_mfma_f64_16x16x4f64((double)lane, 1.0, zz, 0, 0, 0);
    v4d d2 = __builtin_amdgcn_mfma_f64_16x16x4f64(1.0, (double)lane, zz, 0, 0, 0);
    const bool a_h1 = (((int)d1[0] & 3) == 0);
    const bool b_h1 = (((int)d2[0] & 3) == 0);
    int drow[4];
    #pragma unroll
    for (int r = 0; r < 4; ++r) {
        const int v = (int)d1[r];
        drow[r] = (a_h1 ? (v - 96) >> 2 : (v - 6) >> 4) & 15;
    }
    const int am = a_h1 ? (lane & 15) : (lane >> 2);
    const int ak = a_h1 ? (lane >> 4) : (lane & 3);
    const int bn = b_h1 ? (lane & 15) : (lane >> 2);
    const int bk = b_h1 ? (lane >> 4) : (lane & 3);
    const int dcol = lane & 15;

    const int o0 = ob * BM, t0 = tb * BN;
    const float* Wp = W + (size_t)o0 * IN_DIM;
    const float* xp = x + (size_t)b * IN_DIM * T_DIM + t0;
    const int wo = (wave >> 1) * 64, wt = (wave & 1) * 64;

    v4d acc[4][4];
    #pragma unroll
    for (int i = 0; i < 4; ++i)
        #pragma unroll
        for (int j = 0; j < 4; ++j) acc[i][j] = zz;

    const int ar0 = tid / 4, ac = (tid % 4) * 4;
    const int bkr0 = tid / 32, btc = (tid % 32) * 4;

    float4 pa[2], pb[2];
    #pragma unroll
    for (int p = 0; p < 2; ++p) {
        pa[p] = *(const float4*)&Wp[(size_t)(ar0 + p * 64) * IN_DIM + ac];
        pb[p] = *(const float4*)&xp[(size_t)(bkr0 + p * 8) * T_DIM + btc];
    }

    for (int k0 = 0; k0 < IN_DIM; k0 += BK) {
        #pragma unroll
        for (int p = 0; p < 2; ++p) {
            const int r = ar0 + p * 64;
            As[ac + 0][r] = (double)pa[p].x; As[ac + 1][r] = (double)pa[p].y;
            As[ac + 2][r] = (double)pa[p].z; As[ac + 3][r] = (double)pa[p].w;
            const int kr = bkr0 + p * 8;
            Bs[kr][btc + 0] = (double)pb[p].x; Bs[kr][btc + 1] = (double)pb[p].y;
            Bs[kr][btc + 2] = (double)pb[p].z; Bs[kr][btc + 3] = (double)pb[p].w;
        }
        if (k0 + BK < IN_DIM) {
            #pragma unroll
            for (int p = 0; p < 2; ++p) {
                pa[p] = *(const float4*)&Wp[(size_t)(ar0 + p * 64) * IN_DIM + k0 + BK + ac];
                pb[p] = *(const float4*)&xp[(size_t)(bkr0 + p * 8 + k0 + BK) * T_DIM + btc];
            }
        }
        __syncthreads();
        #pragma unroll
        for (int kk = 0; kk < 4; ++kk) {
            const int kra = kk * 4 + ak, krb = kk * 4 + bk;
            double a[4], bb[4];
            #pragma unroll
            for (int i = 0; i < 4; ++i) a[i] = As[kra][wo + i * 16 + am];
            #pragma unroll
            for (int j = 0; j < 4; ++j) bb[j] = Bs[krb][wt + j * 16 + bn];
            #pragma unroll
            for (int i = 0; i < 4; ++i)
                #pragma unroll
                for (int j = 0; j < 4; ++j)
                    acc[i][j] = __builtin_amdgcn_mfma_f64_16x16x4f64(a[i], bb[j], acc[i][j], 0, 0, 0);
        }
        __syncthreads();
    }

    float* ohi = syn_hi + ((size_t)b * OUT_DIM + o0) * T_DIM + t0;
    float* olo = syn_lo + ((size_t)b * OUT_DIM + o0) * T_DIM + t0;
    #pragma unroll
    for (int i = 0; i < 4; ++i)
        #pragma unroll
        for (int j = 0; j < 4; ++j) {
            const int col = wt + j * 16 + dcol;
            #pragma unroll
            for (int r = 0; r < 4; ++r) {
                double s = acc[i][j][r];
                float hi = (float)s;
                float lo = (float)(s - (double)hi);
                const size_t off = (size_t)(wo + i * 16 + drow[r]) * T_DIM + col;
                ohi[off] = hi; olo[off] = lo;
            }
        }
}

// ---------------- scan: f64 LIF, in place over hi (proven) ----------------
__global__ __launch_bounds__(256) void spk_scan_f64_kernel(
    float* __restrict__ hi, const float* __restrict__ lo)
{
    const int TC = 16;
    __shared__ float thi[256][TC + 1];
    __shared__ float tlo[256][TC + 1];
    const int tid = threadIdx.x;
    const size_t row0 = (size_t)blockIdx.x * 256;

    double mem = 0.0;
    for (int t0 = 0; t0 < T_DIM; t0 += TC) {
        #pragma unroll
        for (int p = 0; p < 4; ++p) {
            int id = tid + p * 256;
            int r = id / 4, c = (id % 4) * 4;
            size_t g = (row0 + r) * T_DIM + t0 + c;
            float4 vh = *(const float4*)&hi[g];
            thi[r][c] = vh.x; thi[r][c+1] = vh.y; thi[r][c+2] = vh.z; thi[r][c+3] = vh.w;
            float4 vl = *(const float4*)&lo[g];
            tlo[r][c] = vl.x; tlo[r][c+1] = vl.y; tlo[r][c+2] = vl.z; tlo[r][c+3] = vl.w;
        }
        __syncthreads();
        float spk[TC];
        #pragma unroll
        for (int t = 0; t < TC; ++t) {
            double s = (double)thi[tid][t] + (double)tlo[tid][t];
            double reset = (mem > 1.0) ? 1.0 : 0.0;
            mem = 0.9 * mem + s - reset;
            spk[t] = ((mem - 1.0) > 0.0) ? 1.0f : 0.0f;
        }
        __syncthreads();
        #pragma unroll
        for (int t = 0; t < TC; ++t) thi[tid][t] = spk[t];
        __syncthreads();
        #pragma unroll
        for (int p = 0; p < 4; ++p) {
            int id = tid + p * 256;
            int r = id / 4, c = (id % 4) * 4;
            float4 v = make_float4(thi[r][c], thi[r][c+1], thi[r][c+2], thi[r][c+3]);
            *(float4*)&hi[(row0 + r) * T_DIM + t0 + c] = v;
        }
        __syncthreads();
    }
}

extern "C" void kernel_launch(void* const* d_in, const int* in_sizes, int n_in,
                              void* d_out, int out_size, void* d_ws, size_t ws_size,
                              hipStream_t stream)
{
    const float* x = (const float*)d_in[0];
    const float* W = (const float*)d_in[1];
    float* hi = (float*)d_out;
    char* ws = (char*)d_ws;
    float* lo = (float*)(ws + LO_OFF);

    if (ws_size >= WS_NEED) {
        signed char* wsl = (signed char*)(ws + WSL_OFF);
        signed char* xsl = (signed char*)(ws + XSL_OFF);
        int* alpha = (int*)(ws + AL_OFF);
        int* beta  = (int*)(ws + BE_OFF);
        float* part = (float*)(ws + PART_OFF);

        k_beta_part<<<dim3(16, B_DIM), dim3(256), 0, stream>>>(x, part);
        k_beta<<<dim3(B_DIM), dim3(256), 0, stream>>>(part, beta);
        k_slice_w<<<dim3(OUT_DIM), dim3(256), 0, stream>>>(W, wsl, alpha);
        k_slice_x<<<dim3(4, 16, B_DIM), dim3(256), 0, stream>>>(x, beta, xsl);
        k_oz_gemm<<<dim3(2, 8, B_DIM), dim3(512), 0, stream>>>(wsl, xsl, alpha, beta, hi, lo);
    } else {
        spk_gemm_mfma64p_kernel<<<dim3(2, 8, B_DIM), dim3(256), 0, stream>>>(x, W, hi, lo);
    }
    spk_scan_f64_kernel<<<dim3((B_DIM * OUT_DIM) / 256), dim3(256), 0, stream>>>(hi, lo);
}

// Round 5
// 348.353 us; speedup vs baseline: 1.4459x; 1.1381x over previous
//
#include <hip/hip_runtime.h>

// B=64, IN=1024, OUT=1024, T=256
// syn[b,o,t] = sum_i W[o,i]*x[b,i,t]; spikes via f64 LIF scan.
//
// R15: (a) 4-digit Ozaki, p+q<=3 -> 10 pairs, 20 MFMAs/wave-step. Calibrated
// step model (R11/R12/R14, within 8%): cyc = 9.15*MFMA + LDSbytes/85 + DMA +
// 255. 4-digit: 1464+1129+225+255 = 3073 -> ~164 us GEMM. Numerics: added
// syn error ~1e-7 typ vs the ~2e-6 jax-f32-vs-exact difference already
// absorbed with absmax=0; PRE-COMMIT: absmax>0 -> revert to 5 digits.
// (b) Integer digit extraction in slice kernels: digits = 7-bit slices of
// M<<(be_x-be_m+4), sign applied after — bit-identical to the f64 trunc
// loop, ~6x fewer VALU cycles.
// Geometry/pipeline from R12/R14 (proven): 128x128 block, 8 waves, wave tile
// 32(o)x64(t); triple buffer (3x32KB=96KB LDS), depth-2 prefetch, counted
// s_waitcnt vmcnt(4) (4 gload_lds16/thread/step, 32 segments), setprio(1)
// around MFMA cluster. acc = 8x v16i (128 AGPR). Fragment-ordered wsl/xsl
// (zero bank conflicts), DMA dest = wave-uniform base + lane*16.
// D-placement by runtime probes. Fallback: R6 f64-MFMA path.

#define B_DIM 64
#define IN_DIM 1024
#define OUT_DIM 1024
#define T_DIM 256

typedef int v4i __attribute__((ext_vector_type(4)));
typedef int v16i __attribute__((ext_vector_type(16)));
typedef double v4d __attribute__((ext_vector_type(4)));

// ---------------- workspace layout (bytes) ----------------
#define LO_OFF   0ull                    // 67108864  f32 syn_lo
#define WSL_OFF  67108864ull             // i8 W frags [p:4][o32:32][ks:32][lane:64][16] = 4MB
#define XSL_OFF  73400320ull             // i8 x frags [q:4][b:64][t32:8][ks:32][lane:64][16] = 67MB
#define AL_OFF   174063616ull            // 4096      i32 alpha_e[1024]
#define BE_OFF   174067712ull            // 65536     i32 beta_e[64][256]
#define PART_OFF 174133248ull            // 1048576   f32 partial maxes [64][16][256]
#define WS_NEED  175181824ull

__device__ __forceinline__ void gload_lds16(const void* g, void* l)
{
    __builtin_amdgcn_global_load_lds(
        (const __attribute__((address_space(1))) void*)g,
        (__attribute__((address_space(3))) void*)l, 16, 0, 0);
}

// Integer digit extraction: fix28 = |x|/2^e_col * 2^28 (truncated), digits =
// 7-bit slices, negated if x<0. Bit-identical to the proven f64 trunc loop.
__device__ __forceinline__ void dig4_extract(unsigned bits, int bem,
                                             signed char* d /*4*/)
{
    const int be = (bits >> 23) & 255;
    unsigned M = (bits & 0x7fffffu) | (be ? 0x800000u : 0u);
    const int sh = be - bem + 4;
    unsigned fix = 0;
    if (sh >= 0) fix = M << sh;
    else if (sh > -32) fix = M >> (-sh);
    int d0 = (fix >> 21) & 127, d1 = (fix >> 14) & 127,
        d2 = (fix >> 7) & 127,  d3 = fix & 127;
    if (bits & 0x80000000u) { d0 = -d0; d1 = -d1; d2 = -d2; d3 = -d3; }
    d[0] = (signed char)d0; d[1] = (signed char)d1;
    d[2] = (signed char)d2; d[3] = (signed char)d3;
}

// ---------------- K1a: partial column maxes (proven) ----------------
__global__ __launch_bounds__(256) void k_beta_part(const float* __restrict__ x,
                                                   float* __restrict__ part)
{
    const int ic = blockIdx.x;   // i chunk 0..15
    const int b  = blockIdx.y;
    const int t  = threadIdx.x;
    const float* p = x + ((size_t)b * IN_DIM + ic * 64) * T_DIM + t;
    float m = 0.f;
    #pragma unroll 4
    for (int i = 0; i < 64; ++i) m = fmaxf(m, fabsf(p[(size_t)i * T_DIM]));
    part[((size_t)b * 16 + ic) * T_DIM + t] = m;
}

// ---------------- K1b: beta exponents (proven) ----------------
__global__ __launch_bounds__(256) void k_beta(const float* __restrict__ part,
                                              int* __restrict__ beta_e)
{
    const int b = blockIdx.x, t = threadIdx.x;
    float m = 0.f;
    #pragma unroll
    for (int ic = 0; ic < 16; ++ic)
        m = fmaxf(m, part[((size_t)b * 16 + ic) * T_DIM + t]);
    int e = 0;
    if (m > 0.f) frexpf(m, &e);   // |x|/2^e < 1
    beta_e[b * T_DIM + t] = e;
}

// ---------------- K2: slice x -> fragment order (4 digits, int path) -------
__global__ __launch_bounds__(256) void k_slice_x(const float* __restrict__ x,
    const int* __restrict__ beta_e, signed char* __restrict__ xsl)
{
    __shared__ float ft[64][65];
    const int tb = blockIdx.x;    // 0..3
    const int ib = blockIdx.y;    // 0..15
    const int b  = blockIdx.z;
    const int tid = threadIdx.x;
    const int t0 = tb * 64, i0 = ib * 64;
    #pragma unroll
    for (int p = 0; p < 16; ++p) {
        int id = tid + p * 256;
        int il = id >> 6, tl = id & 63;
        ft[il][tl] = x[((size_t)b * IN_DIM + i0 + il) * T_DIM + t0 + tl];
    }
    __syncthreads();

    const int t32l = tid >> 7;
    const int ksl  = (tid >> 6) & 1;
    const int lane = tid & 63;
    const int t_local = t32l * 32 + (lane & 31);
    const int k_local = ksl * 32 + (lane >> 5) * 16;
    const int e = beta_e[b * T_DIM + t0 + t_local];
    const int bem = e + 126;

    signed char dig[16][4];
    #pragma unroll
    for (int j = 0; j < 16; ++j)
        dig4_extract(__float_as_uint(ft[k_local + j][t_local]), bem, dig[j]);

    #pragma unroll
    for (int p = 0; p < 4; ++p) {
        int w[4];
        #pragma unroll
        for (int g = 0; g < 4; ++g)
            w[g] = (dig[4*g][p] & 0xff) | ((dig[4*g+1][p] & 0xff) << 8) |
                   ((dig[4*g+2][p] & 0xff) << 16) | ((dig[4*g+3][p] & 0xff) << 24);
        const size_t base =
            ((((size_t)p * B_DIM + b) * 8 + (tb * 2 + t32l)) * 32 + (ib * 2 + ksl)) * 1024
            + lane * 16;
        *(v4i*)&xsl[base] = (v4i){w[0], w[1], w[2], w[3]};
    }
}

// ---------------- K3: alpha + slice W (4 digits, int path) --------
__global__ __launch_bounds__(256) void k_slice_w(const float* __restrict__ W,
    signed char* __restrict__ wsl, int* __restrict__ alpha_e)
{
    __shared__ float red[256];
    __shared__ float wrow[1024];
    __shared__ int se;
    const int o = blockIdx.x, tid = threadIdx.x;
    float4 v = *(const float4*)&W[(size_t)o * IN_DIM + tid * 4];
    *(float4*)&wrow[tid * 4] = v;
    float m = fmaxf(fmaxf(fabsf(v.x), fabsf(v.y)), fmaxf(fabsf(v.z), fabsf(v.w)));
    red[tid] = m; __syncthreads();
    for (int s = 128; s > 0; s >>= 1) {
        if (tid < s) red[tid] = fmaxf(red[tid], red[tid + s]);
        __syncthreads();
    }
    if (tid == 0) { int e = 0; if (red[0] > 0.f) frexpf(red[0], &e); se = e; alpha_e[o] = e; }
    __syncthreads();
    if (tid >= 64) return;
    const int bem = se + 126;
    const int ks = tid >> 1, khalf = tid & 1;
    const int k0 = tid * 16;
    const int lane = (o & 31) + 32 * khalf;

    signed char dig[16][4];
    #pragma unroll
    for (int j = 0; j < 16; ++j)
        dig4_extract(__float_as_uint(wrow[k0 + j]), bem, dig[j]);

    #pragma unroll
    for (int p = 0; p < 4; ++p) {
        int w[4];
        #pragma unroll
        for (int g = 0; g < 4; ++g)
            w[g] = (dig[4*g][p] & 0xff) | ((dig[4*g+1][p] & 0xff) << 8) |
                   ((dig[4*g+2][p] & 0xff) << 16) | ((dig[4*g+3][p] & 0xff) << 24);
        const size_t base =
            (((size_t)p * 32 + (o >> 5)) * 32 + ks) * 1024 + lane * 16;
        *(v4i*)&wsl[base] = (v4i){w[0], w[1], w[2], w[3]};
    }
}

// ---------------- K4: Ozaki i8 MFMA GEMM, 128x128, 4 digits ----------------
// 8 waves (512 thr), wave tile 32(o)x64(t). Per k-step per wave: 4 af + 8 bf
// LDS reads, 20 MFMAs. LDS buffer (32KB): 32 segments of 1KB; segment
// s = 8j + wave (j=0..3 per-thread loads). s<16 -> A digit p=s>>2, sub=s&3;
// s>=16 -> B digit q=(s-16)>>2, sub=(s-16)&3. Math: A frag at p*4096 +
// woh*1024; B frag at 16384 + q*4096 + (2*wth+{0,1})*1024.
// Depth-2 triple buffer; steady-state 8 outstanding -> s_waitcnt vmcnt(4)
// retires the oldest tile while the newest stays in flight across s_barrier.
#define OZ_LOADS(PF)                                                        \
    {                                                                       \
        _Pragma("unroll")                                                   \
        for (int j = 0; j < 4; ++j) {                                       \
            gload_lds16(gp[j], &LB[PF][lbase + j * 8192]);                  \
            gp[j] += 1024;                                                  \
        }                                                                   \
    }

#define OZ_MATH(CUR)                                                        \
    {                                                                       \
        const signed char* base_ = LB[CUR];                                 \
        v4i af[4];                                                          \
        _Pragma("unroll")                                                   \
        for (int p = 0; p < 4; ++p)                                         \
            af[p] = *(const v4i*)(base_ + p * 4096 + aoffm);                \
        __builtin_amdgcn_s_setprio(1);                                      \
        _Pragma("unroll")                                                   \
        for (int q = 0; q < 4; ++q) {                                       \
            v4i b0 = *(const v4i*)(base_ + 16384 + q * 4096 + boffm);       \
            v4i b1 = *(const v4i*)(base_ + 16384 + q * 4096 + boffm + 1024);\
            _Pragma("unroll")                                               \
            for (int p = 0; p + q < 4; ++p) {                               \
                accA[p + q] = __builtin_amdgcn_mfma_i32_32x32x32_i8(        \
                    af[p], b0, accA[p + q], 0, 0, 0);                       \
                accB[p + q] = __builtin_amdgcn_mfma_i32_32x32x32_i8(        \
                    af[p], b1, accB[p + q], 0, 0, 0);                       \
            }                                                               \
        }                                                                   \
        __builtin_amdgcn_s_setprio(0);                                      \
    }

#define VMBAR(N)                                                            \
    do {                                                                    \
        asm volatile("s_waitcnt vmcnt(" #N ")" ::: "memory");               \
        __builtin_amdgcn_s_barrier();                                       \
    } while (0)

__global__ __launch_bounds__(512, 2) void k_oz_gemm(
    const signed char* __restrict__ wsl, const signed char* __restrict__ xsl,
    const int* __restrict__ alpha_e, const int* __restrict__ beta_e,
    float* __restrict__ syn_hi, float* __restrict__ syn_lo)
{
    __shared__ __align__(16) signed char LB[3][32768];

    const int tid = threadIdx.x;
    const int lane = tid & 63, wave = tid >> 6;    // wave 0..7
    const int tb = blockIdx.x;   // 0..1 (t block of 128)
    const int ob = blockIdx.y;   // 0..7 (o block of 128)
    const int b  = blockIdx.z;
    const int o0 = ob * 128, t0 = tb * 128;
    const int woh = wave >> 1;   // o sub 0..3 (32 rows each)
    const int wth = wave & 1;    // t half 0..1 (64 cols each)
    const int l16 = lane * 16;

    v16i accA[4], accB[4];
    #pragma unroll
    for (int s = 0; s < 4; ++s) {
        accA[s] = (v16i){0,0,0,0,0,0,0,0,0,0,0,0,0,0,0,0};
        accB[s] = (v16i){0,0,0,0,0,0,0,0,0,0,0,0,0,0,0,0};
    }

    // Staging pointers: segment s = 8j + wave.
    // wsl addr = (p<<20) + (o32<<15) + (kt<<10) + lane*16, o32 = 4*ob+sub.
    // xsl addr = (q<<24) + (b<<18) + (t32<<15) + (kt<<10) + lane*16.
    const signed char* gp[4];
    #pragma unroll
    for (int j = 0; j < 4; ++j) {
        const int s = 8 * j + wave;
        if (s < 16) {
            gp[j] = wsl + ((size_t)(s >> 2) << 20)
                        + ((size_t)(4 * ob + (s & 3)) << 15) + l16;
        } else {
            const int t = s - 16;
            gp[j] = xsl + ((size_t)(t >> 2) << 24) + ((size_t)b << 18)
                        + ((size_t)(4 * tb + (t & 3)) << 15) + l16;
        }
    }
    const int lbase = wave * 1024;   // segment s LDS offset = s*1024 = lbase + j*8192

    // Math-side LDS offsets (fragment reads).
    const int aoffm = woh * 1024 + l16;          // + p*4096          (A region)
    const int boffm = wth * 2048 + l16;          // + 16384 + q*4096  (B region)

    // prologue: kt=0 -> LB[0], kt=1 -> LB[1]; retire kt=0 (vmcnt 8->4).
    OZ_LOADS(0)
    OZ_LOADS(1)
    VMBAR(4);

    // steady state: kt = 0..29, buffers rotate (0,1,2). Never drain to 0.
    #pragma unroll 1
    for (int it = 0; it < 10; ++it) {
        OZ_LOADS(2) OZ_MATH(0) VMBAR(4);
        OZ_LOADS(0) OZ_MATH(1) VMBAR(4);
        OZ_LOADS(1) OZ_MATH(2) VMBAR(4);
    }
    // kt=30: nothing left to issue; drain kt=31's 4 loads, last barrier.
    OZ_MATH(0) VMBAR(0);
    // kt=31: registers only from here on.
    OZ_MATH(1)

    // Runtime D-placement probes (R6/R7 technique).
    const int lr = lane & 31;
    const int rv = (lr + 1) * 0x01010101;
    const v4i pav  = {rv, rv, rv, rv};
    const v4i onev = {0x01010101, 0x01010101, 0x01010101, 0x01010101};
    const v16i z = (v16i){0,0,0,0,0,0,0,0,0,0,0,0,0,0,0,0};
    v16i d1 = __builtin_amdgcn_mfma_i32_32x32x32_i8(pav, onev, z, 0, 0, 0);
    v16i d2 = __builtin_amdgcn_mfma_i32_32x32x32_i8(onev, pav, z, 0, 0, 0);

    const int col = (d2[0] >> 5) - 1;            // 0..31 within tile
    const int gtA = t0 + wth * 64 + col;         // t32 sub 2*wth
    const int gtB = gtA + 32;                    // t32 sub 2*wth+1
    const int ebA = beta_e[b * T_DIM + gtA];
    const int ebB = beta_e[b * T_DIM + gtB];
    float* ohiA = syn_hi + ((size_t)b * OUT_DIM + o0) * T_DIM + gtA;
    float* oloA = syn_lo + ((size_t)b * OUT_DIM + o0) * T_DIM + gtA;

    const double C0 = 0x1p-14, C1 = 0x1p-21, C2 = 0x1p-28, C3 = 0x1p-35;
    #pragma unroll
    for (int r = 0; r < 16; ++r) {
        const int row = (d1[r] >> 5) - 1;        // 0..31 within tile
        const int go = woh * 32 + row;
        const int ea = alpha_e[o0 + go];
        double vA = (double)accA[0][r] * C0 + (double)accA[1][r] * C1 +
                    (double)accA[2][r] * C2 + (double)accA[3][r] * C3;
        double vB = (double)accB[0][r] * C0 + (double)accB[1][r] * C1 +
                    (double)accB[2][r] * C2 + (double)accB[3][r] * C3;
        double synA = ldexp(vA, ea + ebA);
        double synB = ldexp(vB, ea + ebB);
        float hiA = (float)synA;
        float loA = (float)(synA - (double)hiA);
        float hiB = (float)synB;
        float loB = (float)(synB - (double)hiB);
        const size_t off = (size_t)go * T_DIM;
        ohiA[off] = hiA;       oloA[off] = loA;
        ohiA[off + 32] = hiB;  oloA[off + 32] = loB;
    }
}

// ---------------- Fallback GEMM: R6 f64-MFMA with probes (proven) ----------
#define BM 128
#define BN 128
#define BK 16
#define LDA 130

__global__ __launch_bounds__(256, 2) void spk_gemm_mfma64p_kernel(
    const float* __restrict__ x, const float* __restrict__ W,
    float* __restrict__ syn_hi, float* __restrict__ syn_lo)
{
    const int tid  = threadIdx.x;
    const int lane = tid & 63;
    const int wave = tid >> 6;
    const int tb = blockIdx.x, ob = blockIdx.y, b = blockIdx.z;

    __shared__ __align__(16) double As[BK][LDA];
    __shared__ __align__(16) double Bs[BK][LDA];

    const v4d zz = {0.0, 0.0, 0.0, 0.0};
    v4d d1 = __builtin_amdgcn_mfma_f64_16x16x4f64((double)lane, 1.0, zz, 0, 0, 0);
    v4d d2 = __builtin_amdgcn_mfma_f64_16x16x4f64(1.0, (double)lane, zz, 0, 0, 0);
    const bool a_h1 = (((int)d1[0] & 3) == 0);
    const bool b_h1 = (((int)d2[0] & 3) == 0);
    int drow[4];
    #pragma unroll
    for (int r = 0; r < 4; ++r) {
        const int v = (int)d1[r];
        drow[r] = (a_h1 ? (v - 96) >> 2 : (v - 6) >> 4) & 15;
    }
    const int am = a_h1 ? (lane & 15) : (lane >> 2);
    const int ak = a_h1 ? (lane >> 4) : (lane & 3);
    const int bn = b_h1 ? (lane & 15) : (lane >> 2);
    const int bk = b_h1 ? (lane >> 4) : (lane & 3);
    const int dcol = lane & 15;

    const int o0 = ob * BM, t0 = tb * BN;
    const float* Wp = W + (size_t)o0 * IN_DIM;
    const float* xp = x + (size_t)b * IN_DIM * T_DIM + t0;
    const int wo = (wave >> 1) * 64, wt = (wave & 1) * 64;

    v4d acc[4][4];
    #pragma unroll
    for (int i = 0; i < 4; ++i)
        #pragma unroll
        for (int j = 0; j < 4; ++j) acc[i][j] = zz;

    const int ar0 = tid / 4, ac = (tid % 4) * 4;
    const int bkr0 = tid / 32, btc = (tid % 32) * 4;

    float4 pa[2], pb[2];
    #pragma unroll
    for (int p = 0; p < 2; ++p) {
        pa[p] = *(const float4*)&Wp[(size_t)(ar0 + p * 64) * IN_DIM + ac];
        pb[p] = *(const float4*)&xp[(size_t)(bkr0 + p * 8) * T_DIM + btc];
    }

    for (int k0 = 0; k0 < IN_DIM; k0 += BK) {
        #pragma unroll
        for (int p = 0; p < 2; ++p) {
            const int r = ar0 + p * 64;
            As[ac + 0][r] = (double)pa[p].x; As[ac + 1][r] = (double)pa[p].y;
            As[ac + 2][r] = (double)pa[p].z; As[ac + 3][r] = (double)pa[p].w;
            const int kr = bkr0 + p * 8;
            Bs[kr][btc + 0] = (double)pb[p].x; Bs[kr][btc + 1] = (double)pb[p].y;
            Bs[kr][btc + 2] = (double)pb[p].z; Bs[kr][btc + 3] = (double)pb[p].w;
        }
        if (k0 + BK < IN_DIM) {
            #pragma unroll
            for (int p = 0; p < 2; ++p) {
                pa[p] = *(const float4*)&Wp[(size_t)(ar0 + p * 64) * IN_DIM + k0 + BK + ac];
                pb[p] = *(const float4*)&xp[(size_t)(bkr0 + p * 8 + k0 + BK) * T_DIM + btc];
            }
        }
        __syncthreads();
        #pragma unroll
        for (int kk = 0; kk < 4; ++kk) {
            const int kra = kk * 4 + ak, krb = kk * 4 + bk;
            double a[4], bb[4];
            #pragma unroll
            for (int i = 0; i < 4; ++i) a[i] = As[kra][wo + i * 16 + am];
            #pragma unroll
            for (int j = 0; j < 4; ++j) bb[j] = Bs[krb][wt + j * 16 + bn];
            #pragma unroll
            for (int i = 0; i < 4; ++i)
                #pragma unroll
                for (int j = 0; j < 4; ++j)
                    acc[i][j] = __builtin_amdgcn_mfma_f64_16x16x4f64(a[i], bb[j], acc[i][j], 0, 0, 0);
        }
        __syncthreads();
    }

    float* ohi = syn_hi + ((size_t)b * OUT_DIM + o0) * T_DIM + t0;
    float* olo = syn_lo + ((size_t)b * OUT_DIM + o0) * T_DIM + t0;
    #pragma unroll
    for (int i = 0; i < 4; ++i)
        #pragma unroll
        for (int j = 0; j < 4; ++j) {
            const int col = wt + j * 16 + dcol;
            #pragma unroll
            for (int r = 0; r < 4; ++r) {
                double s = acc[i][j][r];
                float hi = (float)s;
                float lo = (float)(s - (double)hi);
                const size_t off = (size_t)(wo + i * 16 + drow[r]) * T_DIM + col;
                ohi[off] = hi; olo[off] = lo;
            }
        }
}

// ---------------- scan: f64 LIF, in place over hi (proven) ----------------
__global__ __launch_bounds__(256) void spk_scan_f64_kernel(
    float* __restrict__ hi, const float* __restrict__ lo)
{
    const int TC = 16;
    __shared__ float thi[256][TC + 1];
    __shared__ float tlo[256][TC + 1];
    const int tid = threadIdx.x;
    const size_t row0 = (size_t)blockIdx.x * 256;

    double mem = 0.0;
    for (int t0 = 0; t0 < T_DIM; t0 += TC) {
        #pragma unroll
        for (int p = 0; p < 4; ++p) {
            int id = tid + p * 256;
            int r = id / 4, c = (id % 4) * 4;
            size_t g = (row0 + r) * T_DIM + t0 + c;
            float4 vh = *(const float4*)&hi[g];
            thi[r][c] = vh.x; thi[r][c+1] = vh.y; thi[r][c+2] = vh.z; thi[r][c+3] = vh.w;
            float4 vl = *(const float4*)&lo[g];
            tlo[r][c] = vl.x; tlo[r][c+1] = vl.y; tlo[r][c+2] = vl.z; tlo[r][c+3] = vl.w;
        }
        __syncthreads();
        float spk[TC];
        #pragma unroll
        for (int t = 0; t < TC; ++t) {
            double s = (double)thi[tid][t] + (double)tlo[tid][t];
            double reset = (mem > 1.0) ? 1.0 : 0.0;
            mem = 0.9 * mem + s - reset;
            spk[t] = ((mem - 1.0) > 0.0) ? 1.0f : 0.0f;
        }
        __syncthreads();
        #pragma unroll
        for (int t = 0; t < TC; ++t) thi[tid][t] = spk[t];
        __syncthreads();
        #pragma unroll
        for (int p = 0; p < 4; ++p) {
            int id = tid + p * 256;
            int r = id / 4, c = (id % 4) * 4;
            float4 v = make_float4(thi[r][c], thi[r][c+1], thi[r][c+2], thi[r][c+3]);
            *(float4*)&hi[(row0 + r) * T_DIM + t0 + c] = v;
        }
        __syncthreads();
    }
}

extern "C" void kernel_launch(void* const* d_in, const int* in_sizes, int n_in,
                              void* d_out, int out_size, void* d_ws, size_t ws_size,
                              hipStream_t stream)
{
    const float* x = (const float*)d_in[0];
    const float* W = (const float*)d_in[1];
    float* hi = (float*)d_out;
    char* ws = (char*)d_ws;
    float* lo = (float*)(ws + LO_OFF);

    if (ws_size >= WS_NEED) {
        signed char* wsl = (signed char*)(ws + WSL_OFF);
        signed char* xsl = (signed char*)(ws + XSL_OFF);
        int* alpha = (int*)(ws + AL_OFF);
        int* beta  = (int*)(ws + BE_OFF);
        float* part = (float*)(ws + PART_OFF);

        k_beta_part<<<dim3(16, B_DIM), dim3(256), 0, stream>>>(x, part);
        k_beta<<<dim3(B_DIM), dim3(256), 0, stream>>>(part, beta);
        k_slice_w<<<dim3(OUT_DIM), dim3(256), 0, stream>>>(W, wsl, alpha);
        k_slice_x<<<dim3(4, 16, B_DIM), dim3(256), 0, stream>>>(x, beta, xsl);
        k_oz_gemm<<<dim3(2, 8, B_DIM), dim3(512), 0, stream>>>(wsl, xsl, alpha, beta, hi, lo);
    } else {
        spk_gemm_mfma64p_kernel<<<dim3(2, 8, B_DIM), dim3(256), 0, stream>>>(x, W, hi, lo);
    }
    spk_scan_f64_kernel<<<dim3((B_DIM * OUT_DIM) / 256), dim3(256), 0, stream>>>(hi, lo);
}

// Round 6
// 346.446 us; speedup vs baseline: 1.4539x; 1.0055x over previous
//
#include <hip/hip_runtime.h>

// B=64, IN=1024, OUT=1024, T=256
// syn[b,o,t] = sum_i W[o,i]*x[b,i,t]; spikes via f64 LIF scan.
//
// R16: scan fused into GEMM epilogue. Block now 64(o)x256(t) (full T),
// grid (16 ob, 64 b); per-chunk (t-quarter) the owning waves write EXACT f64
// syn into LDS [t][o] (transposed, conflict-free scan reads), wave 0 runs the
// 64-step LIF chain (mem in registers across chunks), spikes staged in LDS,
// coalesced float4 writes direct to d_out. Deletes: scan kernel, syn_lo,
// 268MB of HBM round-trip. Numerics: strictly better than hi/lo split.
// GEMM core unchanged from R15 (4-digit Ozaki p+q<=3, 20 MFMAs/wave-step,
// triple buffer 3x40KB, depth-2 prefetch, counted vmcnt(5), setprio).
// Step model (calibrated R11-R15, <8% err): 1464 MFMA + 1129 LDSread +
// ~280 DMA + ~255 misc cyc. Fallback: R6 f64-MFMA + standalone scan.

#define B_DIM 64
#define IN_DIM 1024
#define OUT_DIM 1024
#define T_DIM 256

typedef int v4i __attribute__((ext_vector_type(4)));
typedef int v16i __attribute__((ext_vector_type(16)));
typedef double v4d __attribute__((ext_vector_type(4)));

// ---------------- workspace layout (bytes) ----------------
#define LO_OFF   0ull                    // 67108864  f32 syn_lo (fallback only)
#define WSL_OFF  67108864ull             // i8 W frags [p:4][o32:32][ks:32][lane:64][16] = 4MB
#define XSL_OFF  73400320ull             // i8 x frags [q:4][b:64][t32:8][ks:32][lane:64][16] = 67MB
#define AL_OFF   174063616ull            // 4096      i32 alpha_e[1024]
#define BE_OFF   174067712ull            // 65536     i32 beta_e[64][256]
#define PART_OFF 174133248ull            // 1048576   f32 partial maxes [64][16][256]
#define WS_NEED  175181824ull

__device__ __forceinline__ void gload_lds16(const void* g, void* l)
{
    __builtin_amdgcn_global_load_lds(
        (const __attribute__((address_space(1))) void*)g,
        (__attribute__((address_space(3))) void*)l, 16, 0, 0);
}

// Integer digit extraction: fix28 = |x|/2^e_col * 2^28 (truncated), digits =
// 7-bit slices, negated if x<0. Bit-identical to the proven f64 trunc loop.
__device__ __forceinline__ void dig4_extract(unsigned bits, int bem,
                                             signed char* d /*4*/)
{
    const int be = (bits >> 23) & 255;
    unsigned M = (bits & 0x7fffffu) | (be ? 0x800000u : 0u);
    const int sh = be - bem + 4;
    unsigned fix = 0;
    if (sh >= 0) fix = M << sh;
    else if (sh > -32) fix = M >> (-sh);
    int d0 = (fix >> 21) & 127, d1 = (fix >> 14) & 127,
        d2 = (fix >> 7) & 127,  d3 = fix & 127;
    if (bits & 0x80000000u) { d0 = -d0; d1 = -d1; d2 = -d2; d3 = -d3; }
    d[0] = (signed char)d0; d[1] = (signed char)d1;
    d[2] = (signed char)d2; d[3] = (signed char)d3;
}

// ---------------- K1a: partial column maxes (proven) ----------------
__global__ __launch_bounds__(256) void k_beta_part(const float* __restrict__ x,
                                                   float* __restrict__ part)
{
    const int ic = blockIdx.x;   // i chunk 0..15
    const int b  = blockIdx.y;
    const int t  = threadIdx.x;
    const float* p = x + ((size_t)b * IN_DIM + ic * 64) * T_DIM + t;
    float m = 0.f;
    #pragma unroll 4
    for (int i = 0; i < 64; ++i) m = fmaxf(m, fabsf(p[(size_t)i * T_DIM]));
    part[((size_t)b * 16 + ic) * T_DIM + t] = m;
}

// ---------------- K1b: beta exponents (proven) ----------------
__global__ __launch_bounds__(256) void k_beta(const float* __restrict__ part,
                                              int* __restrict__ beta_e)
{
    const int b = blockIdx.x, t = threadIdx.x;
    float m = 0.f;
    #pragma unroll
    for (int ic = 0; ic < 16; ++ic)
        m = fmaxf(m, part[((size_t)b * 16 + ic) * T_DIM + t]);
    int e = 0;
    if (m > 0.f) frexpf(m, &e);   // |x|/2^e < 1
    beta_e[b * T_DIM + t] = e;
}

// ---------------- K2: slice x -> fragment order (4 digits, int path) -------
__global__ __launch_bounds__(256) void k_slice_x(const float* __restrict__ x,
    const int* __restrict__ beta_e, signed char* __restrict__ xsl)
{
    __shared__ float ft[64][65];
    const int tb = blockIdx.x;    // 0..3
    const int ib = blockIdx.y;    // 0..15
    const int b  = blockIdx.z;
    const int tid = threadIdx.x;
    const int t0 = tb * 64, i0 = ib * 64;
    #pragma unroll
    for (int p = 0; p < 16; ++p) {
        int id = tid + p * 256;
        int il = id >> 6, tl = id & 63;
        ft[il][tl] = x[((size_t)b * IN_DIM + i0 + il) * T_DIM + t0 + tl];
    }
    __syncthreads();

    const int t32l = tid >> 7;
    const int ksl  = (tid >> 6) & 1;
    const int lane = tid & 63;
    const int t_local = t32l * 32 + (lane & 31);
    const int k_local = ksl * 32 + (lane >> 5) * 16;
    const int e = beta_e[b * T_DIM + t0 + t_local];
    const int bem = e + 126;

    signed char dig[16][4];
    #pragma unroll
    for (int j = 0; j < 16; ++j)
        dig4_extract(__float_as_uint(ft[k_local + j][t_local]), bem, dig[j]);

    #pragma unroll
    for (int p = 0; p < 4; ++p) {
        int w[4];
        #pragma unroll
        for (int g = 0; g < 4; ++g)
            w[g] = (dig[4*g][p] & 0xff) | ((dig[4*g+1][p] & 0xff) << 8) |
                   ((dig[4*g+2][p] & 0xff) << 16) | ((dig[4*g+3][p] & 0xff) << 24);
        const size_t base =
            ((((size_t)p * B_DIM + b) * 8 + (tb * 2 + t32l)) * 32 + (ib * 2 + ksl)) * 1024
            + lane * 16;
        *(v4i*)&xsl[base] = (v4i){w[0], w[1], w[2], w[3]};
    }
}

// ---------------- K3: alpha + slice W (4 digits, int path) --------
__global__ __launch_bounds__(256) void k_slice_w(const float* __restrict__ W,
    signed char* __restrict__ wsl, int* __restrict__ alpha_e)
{
    __shared__ float red[256];
    __shared__ float wrow[1024];
    __shared__ int se;
    const int o = blockIdx.x, tid = threadIdx.x;
    float4 v = *(const float4*)&W[(size_t)o * IN_DIM + tid * 4];
    *(float4*)&wrow[tid * 4] = v;
    float m = fmaxf(fmaxf(fabsf(v.x), fabsf(v.y)), fmaxf(fabsf(v.z), fabsf(v.w)));
    red[tid] = m; __syncthreads();
    for (int s = 128; s > 0; s >>= 1) {
        if (tid < s) red[tid] = fmaxf(red[tid], red[tid + s]);
        __syncthreads();
    }
    if (tid == 0) { int e = 0; if (red[0] > 0.f) frexpf(red[0], &e); se = e; alpha_e[o] = e; }
    __syncthreads();
    if (tid >= 64) return;
    const int bem = se + 126;
    const int ks = tid >> 1, khalf = tid & 1;
    const int k0 = tid * 16;
    const int lane = (o & 31) + 32 * khalf;

    signed char dig[16][4];
    #pragma unroll
    for (int j = 0; j < 16; ++j)
        dig4_extract(__float_as_uint(wrow[k0 + j]), bem, dig[j]);

    #pragma unroll
    for (int p = 0; p < 4; ++p) {
        int w[4];
        #pragma unroll
        for (int g = 0; g < 4; ++g)
            w[g] = (dig[4*g][p] & 0xff) | ((dig[4*g+1][p] & 0xff) << 8) |
                   ((dig[4*g+2][p] & 0xff) << 16) | ((dig[4*g+3][p] & 0xff) << 24);
        const size_t base =
            (((size_t)p * 32 + (o >> 5)) * 32 + ks) * 1024 + lane * 16;
        *(v4i*)&wsl[base] = (v4i){w[0], w[1], w[2], w[3]};
    }
}

// ---------------- K4: fused Ozaki i8 GEMM + LIF scan ----------------
// Block 64(o)x256(t), grid (16 ob, 64 b). 8 waves: woh=wave>>2 (o sub of 32),
// wtq=wave&3 (t quarter of 64). Wave tile 32x64, 20 MFMAs/step (unchanged).
// LDS buffer (40KB): 40 segments of 1KB; segment s = 8j + wave (j=0..4).
// s<8 -> A [p=s>>1][osub=s&1]; s>=8 -> u=s-8, B [q=u>>3][t32=u&7].
// Math: af at p*2048 + woh*1024; bf at 8192 + q*8192 + wtq*2048 + {0,1024}.
// vmcnt ledger: 5 loads/thread/step; prologue 10 outstanding -> vmcnt(5);
// never 0 in steady state (proven R11-R15 skeleton).
// Epilogue: 4 t-chunks; synbuf f64 [t:64][o:65] (scan reads contiguous),
// spkbuf f32 [o:64][68]; wave 0 carries mem across chunks.
#define OZ_LOADS(PF)                                                        \
    {                                                                       \
        _Pragma("unroll")                                                   \
        for (int j = 0; j < 5; ++j) {                                       \
            gload_lds16(gp[j], &LB[PF][lbase + j * 8192]);                  \
            gp[j] += 1024;                                                  \
        }                                                                   \
    }

#define OZ_MATH(CUR)                                                        \
    {                                                                       \
        const signed char* base_ = LB[CUR];                                 \
        v4i af[4];                                                          \
        _Pragma("unroll")                                                   \
        for (int p = 0; p < 4; ++p)                                         \
            af[p] = *(const v4i*)(base_ + p * 2048 + aoffm);                \
        __builtin_amdgcn_s_setprio(1);                                      \
        _Pragma("unroll")                                                   \
        for (int q = 0; q < 4; ++q) {                                       \
            v4i b0 = *(const v4i*)(base_ + q * 8192 + boffm);               \
            v4i b1 = *(const v4i*)(base_ + q * 8192 + boffm + 1024);        \
            _Pragma("unroll")                                               \
            for (int p = 0; p + q < 4; ++p) {                               \
                accA[p + q] = __builtin_amdgcn_mfma_i32_32x32x32_i8(        \
                    af[p], b0, accA[p + q], 0, 0, 0);                       \
                accB[p + q] = __builtin_amdgcn_mfma_i32_32x32x32_i8(        \
                    af[p], b1, accB[p + q], 0, 0, 0);                       \
            }                                                               \
        }                                                                   \
        __builtin_amdgcn_s_setprio(0);                                      \
    }

#define VMBAR(N)                                                            \
    do {                                                                    \
        asm volatile("s_waitcnt vmcnt(" #N ")" ::: "memory");               \
        __builtin_amdgcn_s_barrier();                                       \
    } while (0)

__global__ __launch_bounds__(512, 2) void k_oz_gemm_fused(
    const signed char* __restrict__ wsl, const signed char* __restrict__ xsl,
    const int* __restrict__ alpha_e, const int* __restrict__ beta_e,
    float* __restrict__ out)
{
    __shared__ __align__(16) signed char LB[3][40960];

    const int tid = threadIdx.x;
    const int lane = tid & 63, wave = tid >> 6;    // wave 0..7
    const int ob = blockIdx.x;   // 0..15 (o block of 64)
    const int b  = blockIdx.y;
    const int o0 = ob * 64;
    const int woh = wave >> 2;   // o sub 0..1 (32 rows each)
    const int wtq = wave & 3;    // t quarter 0..3 (64 cols each)
    const int l16 = lane * 16;

    v16i accA[4], accB[4];
    #pragma unroll
    for (int s = 0; s < 4; ++s) {
        accA[s] = (v16i){0,0,0,0,0,0,0,0,0,0,0,0,0,0,0,0};
        accB[s] = (v16i){0,0,0,0,0,0,0,0,0,0,0,0,0,0,0,0};
    }

    // Staging pointers: segment s = 8j + wave.
    // wsl addr = (p<<20) + (o32<<15) + (kt<<10) + lane*16, o32 = 2*ob + osub.
    // xsl addr = (q<<24) + (b<<18) + (t32<<15) + (kt<<10) + lane*16.
    const signed char* gp[5];
    #pragma unroll
    for (int j = 0; j < 5; ++j) {
        const int s = 8 * j + wave;
        if (s < 8) {
            gp[j] = wsl + ((size_t)(s >> 1) << 20)
                        + ((size_t)(2 * ob + (s & 1)) << 15) + l16;
        } else {
            const int u = s - 8;
            gp[j] = xsl + ((size_t)(u >> 3) << 24) + ((size_t)b << 18)
                        + ((size_t)(u & 7) << 15) + l16;
        }
    }
    const int lbase = wave * 1024;   // segment s LDS offset = s*1024

    // Math-side LDS offsets.
    const int aoffm = woh * 1024 + l16;            // + p*2048 (A region [0,8192))
    const int boffm = 8192 + wtq * 2048 + l16;     // + q*8192 (B region)

    // prologue: kt=0 -> LB[0], kt=1 -> LB[1]; retire kt=0 (vmcnt 10->5).
    OZ_LOADS(0)
    OZ_LOADS(1)
    VMBAR(5);

    // steady state: kt = 0..29, buffers rotate (0,1,2). Never drain to 0.
    #pragma unroll 1
    for (int it = 0; it < 10; ++it) {
        OZ_LOADS(2) OZ_MATH(0) VMBAR(5);
        OZ_LOADS(0) OZ_MATH(1) VMBAR(5);
        OZ_LOADS(1) OZ_MATH(2) VMBAR(5);
    }
    // kt=30: drain kt=31's 5 loads, last barrier.
    OZ_MATH(0) VMBAR(0);
    // kt=31: registers only.
    OZ_MATH(1)

    // Runtime D-placement probes (R6/R7 technique).
    const int lr = lane & 31;
    const int rv = (lr + 1) * 0x01010101;
    const v4i pav  = {rv, rv, rv, rv};
    const v4i onev = {0x01010101, 0x01010101, 0x01010101, 0x01010101};
    const v16i z = (v16i){0,0,0,0,0,0,0,0,0,0,0,0,0,0,0,0};
    v16i d1 = __builtin_amdgcn_mfma_i32_32x32x32_i8(pav, onev, z, 0, 0, 0);
    v16i d2 = __builtin_amdgcn_mfma_i32_32x32x32_i8(onev, pav, z, 0, 0, 0);

    const int col = (d2[0] >> 5) - 1;            // 0..31 within tile
    const int gtA = wtq * 64 + col;              // global t of accA column
    const int gtB = gtA + 32;                    // accB column
    const int ebA = beta_e[b * T_DIM + gtA];
    const int ebB = beta_e[b * T_DIM + gtB];

    // Exact f64 syn per (r, A/B); acc dies here (frees AGPRs for the scan).
    const double C0 = 0x1p-14, C1 = 0x1p-21, C2 = 0x1p-28, C3 = 0x1p-35;
    double synA_[16], synB_[16];
    int go_[16];
    #pragma unroll
    for (int r = 0; r < 16; ++r) {
        const int row = (d1[r] >> 5) - 1;        // 0..31 within tile
        const int go = woh * 32 + row;
        go_[r] = go;
        const int ea = alpha_e[o0 + go];
        double vA = (double)accA[0][r] * C0 + (double)accA[1][r] * C1 +
                    (double)accA[2][r] * C2 + (double)accA[3][r] * C3;
        double vB = (double)accB[0][r] * C0 + (double)accB[1][r] * C1 +
                    (double)accB[2][r] * C2 + (double)accB[3][r] * C3;
        synA_[r] = ldexp(vA, ea + ebA);
        synB_[r] = ldexp(vB, ea + ebB);
    }

    // ---- fused LIF scan over 4 t-chunks of 64 ----
    double* synbuf = (double*)&LB[0][0];   // [t:64][o:65] (pad: 2-way max)
    float*  spkbuf = (float*)&LB[1][0];    // [o:64][68] (float4-aligned rows)
    float*  outp = out + ((size_t)b * OUT_DIM + o0) * T_DIM;
    double mem = 0.0;                      // valid in wave 0 lanes (o-rows)

    __syncthreads();
    #pragma unroll 1
    for (int c = 0; c < 4; ++c) {
        if (wtq == c) {
            #pragma unroll
            for (int r = 0; r < 16; ++r) {
                synbuf[(size_t)col * 65 + go_[r]]        = synA_[r];
                synbuf[(size_t)(col + 32) * 65 + go_[r]] = synB_[r];
            }
        }
        __syncthreads();
        if (wave == 0) {
            #pragma unroll 8
            for (int tt = 0; tt < 64; ++tt) {
                double s = synbuf[(size_t)tt * 65 + lane];
                double reset = (mem > 1.0) ? 1.0 : 0.0;
                mem = 0.9 * mem + s - reset;
                spkbuf[lane * 68 + tt] = ((mem - 1.0) > 0.0) ? 1.0f : 0.0f;
            }
        }
        __syncthreads();
        {
            const int o = tid >> 3, tg = tid & 7;
            float4 v0 = *(float4*)&spkbuf[o * 68 + tg * 8];
            float4 v1 = *(float4*)&spkbuf[o * 68 + tg * 8 + 4];
            float* dst = outp + (size_t)o * T_DIM + c * 64 + tg * 8;
            *(float4*)&dst[0] = v0;
            *(float4*)&dst[4] = v1;
        }
        __syncthreads();
    }
}

// ---------------- Fallback GEMM: R6 f64-MFMA with probes (proven) ----------
#define BM 128
#define BN 128
#define BK 16
#define LDA 130

__global__ __launch_bounds__(256, 2) void spk_gemm_mfma64p_kernel(
    const float* __restrict__ x, const float* __restrict__ W,
    float* __restrict__ syn_hi, float* __restrict__ syn_lo)
{
    const int tid  = threadIdx.x;
    const int lane = tid & 63;
    const int wave = tid >> 6;
    const int tb = blockIdx.x, ob = blockIdx.y, b = blockIdx.z;

    __shared__ __align__(16) double As[BK][LDA];
    __shared__ __align__(16) double Bs[BK][LDA];

    const v4d zz = {0.0, 0.0, 0.0, 0.0};
    v4d d1 = __builtin_amdgcn_mfma_f64_16x16x4f64((double)lane, 1.0, zz, 0, 0, 0);
    v4d d2 = __builtin_amdgcn_mfma_f64_16x16x4f64(1.0, (double)lane, zz, 0, 0, 0);
    const bool a_h1 = (((int)d1[0] & 3) == 0);
    const bool b_h1 = (((int)d2[0] & 3) == 0);
    int drow[4];
    #pragma unroll
    for (int r = 0; r < 4; ++r) {
        const int v = (int)d1[r];
        drow[r] = (a_h1 ? (v - 96) >> 2 : (v - 6) >> 4) & 15;
    }
    const int am = a_h1 ? (lane & 15) : (lane >> 2);
    const int ak = a_h1 ? (lane >> 4) : (lane & 3);
    const int bn = b_h1 ? (lane & 15) : (lane >> 2);
    const int bk = b_h1 ? (lane >> 4) : (lane & 3);
    const int dcol = lane & 15;

    const int o0 = ob * BM, t0 = tb * BN;
    const float* Wp = W + (size_t)o0 * IN_DIM;
    const float* xp = x + (size_t)b * IN_DIM * T_DIM + t0;
    const int wo = (wave >> 1) * 64, wt = (wave & 1) * 64;

    v4d acc[4][4];
    #pragma unroll
    for (int i = 0; i < 4; ++i)
        #pragma unroll
        for (int j = 0; j < 4; ++j) acc[i][j] = zz;

    const int ar0 = tid / 4, ac = (tid % 4) * 4;
    const int bkr0 = tid / 32, btc = (tid % 32) * 4;

    float4 pa[2], pb[2];
    #pragma unroll
    for (int p = 0; p < 2; ++p) {
        pa[p] = *(const float4*)&Wp[(size_t)(ar0 + p * 64) * IN_DIM + ac];
        pb[p] = *(const float4*)&xp[(size_t)(bkr0 + p * 8) * T_DIM + btc];
    }

    for (int k0 = 0; k0 < IN_DIM; k0 += BK) {
        #pragma unroll
        for (int p = 0; p < 2; ++p) {
            const int r = ar0 + p * 64;
            As[ac + 0][r] = (double)pa[p].x; As[ac + 1][r] = (double)pa[p].y;
            As[ac + 2][r] = (double)pa[p].z; As[ac + 3][r] = (double)pa[p].w;
            const int kr = bkr0 + p * 8;
            Bs[kr][btc + 0] = (double)pb[p].x; Bs[kr][btc + 1] = (double)pb[p].y;
            Bs[kr][btc + 2] = (double)pb[p].z; Bs[kr][btc + 3] = (double)pb[p].w;
        }
        if (k0 + BK < IN_DIM) {
            #pragma unroll
            for (int p = 0; p < 2; ++p) {
                pa[p] = *(const float4*)&Wp[(size_t)(ar0 + p * 64) * IN_DIM + k0 + BK + ac];
                pb[p] = *(const float4*)&xp[(size_t)(bkr0 + p * 8 + k0 + BK) * T_DIM + btc];
            }
        }
        __syncthreads();
        #pragma unroll
        for (int kk = 0; kk < 4; ++kk) {
            const int kra = kk * 4 + ak, krb = kk * 4 + bk;
            double a[4], bb[4];
            #pragma unroll
            for (int i = 0; i < 4; ++i) a[i] = As[kra][wo + i * 16 + am];
            #pragma unroll
            for (int j = 0; j < 4; ++j) bb[j] = Bs[krb][wt + j * 16 + bn];
            #pragma unroll
            for (int i = 0; i < 4; ++i)
                #pragma unroll
                for (int j = 0; j < 4; ++j)
                    acc[i][j] = __builtin_amdgcn_mfma_f64_16x16x4f64(a[i], bb[j], acc[i][j], 0, 0, 0);
        }
        __syncthreads();
    }

    float* ohi = syn_hi + ((size_t)b * OUT_DIM + o0) * T_DIM + t0;
    float* olo = syn_lo + ((size_t)b * OUT_DIM + o0) * T_DIM + t0;
    #pragma unroll
    for (int i = 0; i < 4; ++i)
        #pragma unroll
        for (int j = 0; j < 4; ++j) {
            const int col = wt + j * 16 + dcol;
            #pragma unroll
            for (int r = 0; r < 4; ++r) {
                double s = acc[i][j][r];
                float hi = (float)s;
                float lo = (float)(s - (double)hi);
                const size_t off = (size_t)(wo + i * 16 + drow[r]) * T_DIM + col;
                ohi[off] = hi; olo[off] = lo;
            }
        }
}

// ---------------- scan: f64 LIF, in place over hi (fallback only) ----------
__global__ __launch_bounds__(256) void spk_scan_f64_kernel(
    float* __restrict__ hi, const float* __restrict__ lo)
{
    const int TC = 16;
    __shared__ float thi[256][TC + 1];
    __shared__ float tlo[256][TC + 1];
    const int tid = threadIdx.x;
    const size_t row0 = (size_t)blockIdx.x * 256;

    double mem = 0.0;
    for (int t0 = 0; t0 < T_DIM; t0 += TC) {
        #pragma unroll
        for (int p = 0; p < 4; ++p) {
            int id = tid + p * 256;
            int r = id / 4, c = (id % 4) * 4;
            size_t g = (row0 + r) * T_DIM + t0 + c;
            float4 vh = *(const float4*)&hi[g];
            thi[r][c] = vh.x; thi[r][c+1] = vh.y; thi[r][c+2] = vh.z; thi[r][c+3] = vh.w;
            float4 vl = *(const float4*)&lo[g];
            tlo[r][c] = vl.x; tlo[r][c+1] = vl.y; tlo[r][c+2] = vl.z; tlo[r][c+3] = vl.w;
        }
        __syncthreads();
        float spk[TC];
        #pragma unroll
        for (int t = 0; t < TC; ++t) {
            double s = (double)thi[tid][t] + (double)tlo[tid][t];
            double reset = (mem > 1.0) ? 1.0 : 0.0;
            mem = 0.9 * mem + s - reset;
            spk[t] = ((mem - 1.0) > 0.0) ? 1.0f : 0.0f;
        }
        __syncthreads();
        #pragma unroll
        for (int t = 0; t < TC; ++t) thi[tid][t] = spk[t];
        __syncthreads();
        #pragma unroll
        for (int p = 0; p < 4; ++p) {
            int id = tid + p * 256;
            int r = id / 4, c = (id % 4) * 4;
            float4 v = make_float4(thi[r][c], thi[r][c+1], thi[r][c+2], thi[r][c+3]);
            *(float4*)&hi[(row0 + r) * T_DIM + t0 + c] = v;
        }
        __syncthreads();
    }
}

extern "C" void kernel_launch(void* const* d_in, const int* in_sizes, int n_in,
                              void* d_out, int out_size, void* d_ws, size_t ws_size,
                              hipStream_t stream)
{
    const float* x = (const float*)d_in[0];
    const float* W = (const float*)d_in[1];
    float* hi = (float*)d_out;
    char* ws = (char*)d_ws;
    float* lo = (float*)(ws + LO_OFF);

    if (ws_size >= WS_NEED) {
        signed char* wsl = (signed char*)(ws + WSL_OFF);
        signed char* xsl = (signed char*)(ws + XSL_OFF);
        int* alpha = (int*)(ws + AL_OFF);
        int* beta  = (int*)(ws + BE_OFF);
        float* part = (float*)(ws + PART_OFF);

        k_beta_part<<<dim3(16, B_DIM), dim3(256), 0, stream>>>(x, part);
        k_beta<<<dim3(B_DIM), dim3(256), 0, stream>>>(part, beta);
        k_slice_w<<<dim3(OUT_DIM), dim3(256), 0, stream>>>(W, wsl, alpha);
        k_slice_x<<<dim3(4, 16, B_DIM), dim3(256), 0, stream>>>(x, beta, xsl);
        k_oz_gemm_fused<<<dim3(16, B_DIM), dim3(512), 0, stream>>>(wsl, xsl, alpha, beta, hi);
    } else {
        spk_gemm_mfma64p_kernel<<<dim3(2, 8, B_DIM), dim3(256), 0, stream>>>(x, W, hi, lo);
        spk_scan_f64_kernel<<<dim3((B_DIM * OUT_DIM) / 256), dim3(256), 0, stream>>>(hi, lo);
    }
}

// Round 7
// 331.047 us; speedup vs baseline: 1.5215x; 1.0465x over previous
//
#include <hip/hip_runtime.h>

// B=64, IN=1024, OUT=1024, T=256
// syn[b,o,t] = sum_i W[o,i]*x[b,i,t]; spikes via f64 LIF scan.
//
// R17: de-aliased scan epilogue + XCD b-locality swizzle.
// R16 post-mortem: fused scan cost 96 cyc/t-step because synbuf reads and
// spkbuf writes interleave and both derive from LB -> compiler serializes
// (alias). Fix: batch-16 reads into regs, keep ALL 64 spikes in regs, write
// float4s once at the end -> reads hoist/pipeline, ~12 cyc/step.
// Swizzle: 1D grid 1024, b=(r&7)*8+(r>>3), ob=bid>>6 (bijective) -> same-b
// blocks share an XCD under round-robin dispatch; xsl fetched ~once/XCD.
// GEMM core unchanged (4-digit Ozaki p+q<=3, 20 MFMAs/wave-step, triple
// buffer 3x40KB, depth-2 prefetch, counted vmcnt(5), setprio; proven
// R11-R16). Fallback: R6 f64-MFMA + standalone scan.

#define B_DIM 64
#define IN_DIM 1024
#define OUT_DIM 1024
#define T_DIM 256

typedef int v4i __attribute__((ext_vector_type(4)));
typedef int v16i __attribute__((ext_vector_type(16)));
typedef double v4d __attribute__((ext_vector_type(4)));

// ---------------- workspace layout (bytes) ----------------
#define LO_OFF   0ull                    // 67108864  f32 syn_lo (fallback only)
#define WSL_OFF  67108864ull             // i8 W frags [p:4][o32:32][ks:32][lane:64][16] = 4MB
#define XSL_OFF  73400320ull             // i8 x frags [q:4][b:64][t32:8][ks:32][lane:64][16] = 67MB
#define AL_OFF   174063616ull            // 4096      i32 alpha_e[1024]
#define BE_OFF   174067712ull            // 65536     i32 beta_e[64][256]
#define PART_OFF 174133248ull            // 1048576   f32 partial maxes [64][16][256]
#define WS_NEED  175181824ull

__device__ __forceinline__ void gload_lds16(const void* g, void* l)
{
    __builtin_amdgcn_global_load_lds(
        (const __attribute__((address_space(1))) void*)g,
        (__attribute__((address_space(3))) void*)l, 16, 0, 0);
}

// Integer digit extraction: fix28 = |x|/2^e_col * 2^28 (truncated), digits =
// 7-bit slices, negated if x<0. Bit-identical to the proven f64 trunc loop.
__device__ __forceinline__ void dig4_extract(unsigned bits, int bem,
                                             signed char* d /*4*/)
{
    const int be = (bits >> 23) & 255;
    unsigned M = (bits & 0x7fffffu) | (be ? 0x800000u : 0u);
    const int sh = be - bem + 4;
    unsigned fix = 0;
    if (sh >= 0) fix = M << sh;
    else if (sh > -32) fix = M >> (-sh);
    int d0 = (fix >> 21) & 127, d1 = (fix >> 14) & 127,
        d2 = (fix >> 7) & 127,  d3 = fix & 127;
    if (bits & 0x80000000u) { d0 = -d0; d1 = -d1; d2 = -d2; d3 = -d3; }
    d[0] = (signed char)d0; d[1] = (signed char)d1;
    d[2] = (signed char)d2; d[3] = (signed char)d3;
}

// ---------------- K1a: partial column maxes (proven) ----------------
__global__ __launch_bounds__(256) void k_beta_part(const float* __restrict__ x,
                                                   float* __restrict__ part)
{
    const int ic = blockIdx.x;   // i chunk 0..15
    const int b  = blockIdx.y;
    const int t  = threadIdx.x;
    const float* p = x + ((size_t)b * IN_DIM + ic * 64) * T_DIM + t;
    float m = 0.f;
    #pragma unroll 4
    for (int i = 0; i < 64; ++i) m = fmaxf(m, fabsf(p[(size_t)i * T_DIM]));
    part[((size_t)b * 16 + ic) * T_DIM + t] = m;
}

// ---------------- K1b: beta exponents (proven) ----------------
__global__ __launch_bounds__(256) void k_beta(const float* __restrict__ part,
                                              int* __restrict__ beta_e)
{
    const int b = blockIdx.x, t = threadIdx.x;
    float m = 0.f;
    #pragma unroll
    for (int ic = 0; ic < 16; ++ic)
        m = fmaxf(m, part[((size_t)b * 16 + ic) * T_DIM + t]);
    int e = 0;
    if (m > 0.f) frexpf(m, &e);   // |x|/2^e < 1
    beta_e[b * T_DIM + t] = e;
}

// ---------------- K2: slice x -> fragment order (4 digits, int path) -------
__global__ __launch_bounds__(256) void k_slice_x(const float* __restrict__ x,
    const int* __restrict__ beta_e, signed char* __restrict__ xsl)
{
    __shared__ float ft[64][65];
    const int tb = blockIdx.x;    // 0..3
    const int ib = blockIdx.y;    // 0..15
    const int b  = blockIdx.z;
    const int tid = threadIdx.x;
    const int t0 = tb * 64, i0 = ib * 64;
    #pragma unroll
    for (int p = 0; p < 16; ++p) {
        int id = tid + p * 256;
        int il = id >> 6, tl = id & 63;
        ft[il][tl] = x[((size_t)b * IN_DIM + i0 + il) * T_DIM + t0 + tl];
    }
    __syncthreads();

    const int t32l = tid >> 7;
    const int ksl  = (tid >> 6) & 1;
    const int lane = tid & 63;
    const int t_local = t32l * 32 + (lane & 31);
    const int k_local = ksl * 32 + (lane >> 5) * 16;
    const int e = beta_e[b * T_DIM + t0 + t_local];
    const int bem = e + 126;

    signed char dig[16][4];
    #pragma unroll
    for (int j = 0; j < 16; ++j)
        dig4_extract(__float_as_uint(ft[k_local + j][t_local]), bem, dig[j]);

    #pragma unroll
    for (int p = 0; p < 4; ++p) {
        int w[4];
        #pragma unroll
        for (int g = 0; g < 4; ++g)
            w[g] = (dig[4*g][p] & 0xff) | ((dig[4*g+1][p] & 0xff) << 8) |
                   ((dig[4*g+2][p] & 0xff) << 16) | ((dig[4*g+3][p] & 0xff) << 24);
        const size_t base =
            ((((size_t)p * B_DIM + b) * 8 + (tb * 2 + t32l)) * 32 + (ib * 2 + ksl)) * 1024
            + lane * 16;
        *(v4i*)&xsl[base] = (v4i){w[0], w[1], w[2], w[3]};
    }
}

// ---------------- K3: alpha + slice W (4 digits, int path) --------
__global__ __launch_bounds__(256) void k_slice_w(const float* __restrict__ W,
    signed char* __restrict__ wsl, int* __restrict__ alpha_e)
{
    __shared__ float red[256];
    __shared__ float wrow[1024];
    __shared__ int se;
    const int o = blockIdx.x, tid = threadIdx.x;
    float4 v = *(const float4*)&W[(size_t)o * IN_DIM + tid * 4];
    *(float4*)&wrow[tid * 4] = v;
    float m = fmaxf(fmaxf(fabsf(v.x), fabsf(v.y)), fmaxf(fabsf(v.z), fabsf(v.w)));
    red[tid] = m; __syncthreads();
    for (int s = 128; s > 0; s >>= 1) {
        if (tid < s) red[tid] = fmaxf(red[tid], red[tid + s]);
        __syncthreads();
    }
    if (tid == 0) { int e = 0; if (red[0] > 0.f) frexpf(red[0], &e); se = e; alpha_e[o] = e; }
    __syncthreads();
    if (tid >= 64) return;
    const int bem = se + 126;
    const int ks = tid >> 1, khalf = tid & 1;
    const int k0 = tid * 16;
    const int lane = (o & 31) + 32 * khalf;

    signed char dig[16][4];
    #pragma unroll
    for (int j = 0; j < 16; ++j)
        dig4_extract(__float_as_uint(wrow[k0 + j]), bem, dig[j]);

    #pragma unroll
    for (int p = 0; p < 4; ++p) {
        int w[4];
        #pragma unroll
        for (int g = 0; g < 4; ++g)
            w[g] = (dig[4*g][p] & 0xff) | ((dig[4*g+1][p] & 0xff) << 8) |
                   ((dig[4*g+2][p] & 0xff) << 16) | ((dig[4*g+3][p] & 0xff) << 24);
        const size_t base =
            (((size_t)p * 32 + (o >> 5)) * 32 + ks) * 1024 + lane * 16;
        *(v4i*)&wsl[base] = (v4i){w[0], w[1], w[2], w[3]};
    }
}

// ---------------- K4: fused Ozaki i8 GEMM + LIF scan ----------------
// Block 64(o)x256(t), 1D grid 1024 with XCD swizzle: ob=bid>>6, r=bid&63,
// b=(r&7)*8+(r>>3). 8 waves: woh=wave>>2 (o sub), wtq=wave&3 (t quarter).
// Wave tile 32x64, 20 MFMAs/step. LDS buffer (40KB): 40 segments of 1KB;
// segment s = 8j + wave. s<8 -> A [p=s>>1][osub=s&1]; s>=8 -> u=s-8,
// B [q=u>>3][t32=u&7]. vmcnt ledger: 5 loads/thread/step, vmcnt(5) steady,
// drain once at kt=30 (proven R11-R16 skeleton).
// Epilogue: 4 t-chunks; synbuf f64 [t:64][o:65]; wave 0 scans with batch-16
// reg reads, ALL spikes in regs, float4 writes at end (no read/write alias).
#define OZ_LOADS(PF)                                                        \
    {                                                                       \
        _Pragma("unroll")                                                   \
        for (int j = 0; j < 5; ++j) {                                       \
            gload_lds16(gp[j], &LB[PF][lbase + j * 8192]);                  \
            gp[j] += 1024;                                                  \
        }                                                                   \
    }

#define OZ_MATH(CUR)                                                        \
    {                                                                       \
        const signed char* base_ = LB[CUR];                                 \
        v4i af[4];                                                          \
        _Pragma("unroll")                                                   \
        for (int p = 0; p < 4; ++p)                                         \
            af[p] = *(const v4i*)(base_ + p * 2048 + aoffm);                \
        __builtin_amdgcn_s_setprio(1);                                      \
        _Pragma("unroll")                                                   \
        for (int q = 0; q < 4; ++q) {                                       \
            v4i b0 = *(const v4i*)(base_ + q * 8192 + boffm);               \
            v4i b1 = *(const v4i*)(base_ + q * 8192 + boffm + 1024);        \
            _Pragma("unroll")                                               \
            for (int p = 0; p + q < 4; ++p) {                               \
                accA[p + q] = __builtin_amdgcn_mfma_i32_32x32x32_i8(        \
                    af[p], b0, accA[p + q], 0, 0, 0);                       \
                accB[p + q] = __builtin_amdgcn_mfma_i32_32x32x32_i8(        \
                    af[p], b1, accB[p + q], 0, 0, 0);                       \
            }                                                               \
        }                                                                   \
        __builtin_amdgcn_s_setprio(0);                                      \
    }

#define VMBAR(N)                                                            \
    do {                                                                    \
        asm volatile("s_waitcnt vmcnt(" #N ")" ::: "memory");               \
        __builtin_amdgcn_s_barrier();                                       \
    } while (0)

__global__ __launch_bounds__(512, 2) void k_oz_gemm_fused(
    const signed char* __restrict__ wsl, const signed char* __restrict__ xsl,
    const int* __restrict__ alpha_e, const int* __restrict__ beta_e,
    float* __restrict__ out)
{
    __shared__ __align__(16) signed char LB[3][40960];

    const int tid = threadIdx.x;
    const int lane = tid & 63, wave = tid >> 6;    // wave 0..7
    const int bid = blockIdx.x;
    const int ob = bid >> 6;                       // 0..15 (o block of 64)
    const int rr = bid & 63;
    const int b  = ((rr & 7) << 3) + (rr >> 3);    // bijective XCD swizzle
    const int o0 = ob * 64;
    const int woh = wave >> 2;   // o sub 0..1 (32 rows each)
    const int wtq = wave & 3;    // t quarter 0..3 (64 cols each)
    const int l16 = lane * 16;

    v16i accA[4], accB[4];
    #pragma unroll
    for (int s = 0; s < 4; ++s) {
        accA[s] = (v16i){0,0,0,0,0,0,0,0,0,0,0,0,0,0,0,0};
        accB[s] = (v16i){0,0,0,0,0,0,0,0,0,0,0,0,0,0,0,0};
    }

    // Staging pointers: segment s = 8j + wave.
    // wsl addr = (p<<20) + (o32<<15) + (kt<<10) + lane*16, o32 = 2*ob + osub.
    // xsl addr = (q<<24) + (b<<18) + (t32<<15) + (kt<<10) + lane*16.
    const signed char* gp[5];
    #pragma unroll
    for (int j = 0; j < 5; ++j) {
        const int s = 8 * j + wave;
        if (s < 8) {
            gp[j] = wsl + ((size_t)(s >> 1) << 20)
                        + ((size_t)(2 * ob + (s & 1)) << 15) + l16;
        } else {
            const int u = s - 8;
            gp[j] = xsl + ((size_t)(u >> 3) << 24) + ((size_t)b << 18)
                        + ((size_t)(u & 7) << 15) + l16;
        }
    }
    const int lbase = wave * 1024;   // segment s LDS offset = s*1024

    // Math-side LDS offsets.
    const int aoffm = woh * 1024 + l16;            // + p*2048 (A region [0,8192))
    const int boffm = 8192 + wtq * 2048 + l16;     // + q*8192 (B region)

    // prologue: kt=0 -> LB[0], kt=1 -> LB[1]; retire kt=0 (vmcnt 10->5).
    OZ_LOADS(0)
    OZ_LOADS(1)
    VMBAR(5);

    // steady state: kt = 0..29, buffers rotate (0,1,2). Never drain to 0.
    #pragma unroll 1
    for (int it = 0; it < 10; ++it) {
        OZ_LOADS(2) OZ_MATH(0) VMBAR(5);
        OZ_LOADS(0) OZ_MATH(1) VMBAR(5);
        OZ_LOADS(1) OZ_MATH(2) VMBAR(5);
    }
    // kt=30: drain kt=31's 5 loads, last barrier.
    OZ_MATH(0) VMBAR(0);
    // kt=31: registers only.
    OZ_MATH(1)

    // Runtime D-placement probes (R6/R7 technique).
    const int lr = lane & 31;
    const int rv = (lr + 1) * 0x01010101;
    const v4i pav  = {rv, rv, rv, rv};
    const v4i onev = {0x01010101, 0x01010101, 0x01010101, 0x01010101};
    const v16i z = (v16i){0,0,0,0,0,0,0,0,0,0,0,0,0,0,0,0};
    v16i d1 = __builtin_amdgcn_mfma_i32_32x32x32_i8(pav, onev, z, 0, 0, 0);
    v16i d2 = __builtin_amdgcn_mfma_i32_32x32x32_i8(onev, pav, z, 0, 0, 0);

    const int col = (d2[0] >> 5) - 1;            // 0..31 within tile
    const int gtA = wtq * 64 + col;              // global t of accA column
    const int gtB = gtA + 32;                    // accB column
    const int ebA = beta_e[b * T_DIM + gtA];
    const int ebB = beta_e[b * T_DIM + gtB];

    // Exact f64 syn per (r, A/B); acc dies here.
    const double C0 = 0x1p-14, C1 = 0x1p-21, C2 = 0x1p-28, C3 = 0x1p-35;
    double synA_[16], synB_[16];
    int go_[16];
    #pragma unroll
    for (int r = 0; r < 16; ++r) {
        const int row = (d1[r] >> 5) - 1;        // 0..31 within tile
        const int go = woh * 32 + row;
        go_[r] = go;
        const int ea = alpha_e[o0 + go];
        double vA = (double)accA[0][r] * C0 + (double)accA[1][r] * C1 +
                    (double)accA[2][r] * C2 + (double)accA[3][r] * C3;
        double vB = (double)accB[0][r] * C0 + (double)accB[1][r] * C1 +
                    (double)accB[2][r] * C2 + (double)accB[3][r] * C3;
        synA_[r] = ldexp(vA, ea + ebA);
        synB_[r] = ldexp(vB, ea + ebB);
    }

    // ---- fused LIF scan over 4 t-chunks of 64 ----
    double* synbuf = (double*)&LB[0][0];   // [t:64][o:65]
    float*  spkbuf = (float*)&LB[1][0];    // [o:64][68] (float4-aligned rows)
    float*  outp = out + ((size_t)b * OUT_DIM + o0) * T_DIM;
    double mem = 0.0;                      // valid in wave 0 lanes (o-rows)

    __syncthreads();
    #pragma unroll 1
    for (int c = 0; c < 4; ++c) {
        if (wtq == c) {
            #pragma unroll
            for (int r = 0; r < 16; ++r) {
                synbuf[(size_t)col * 65 + go_[r]]        = synA_[r];
                synbuf[(size_t)(col + 32) * 65 + go_[r]] = synB_[r];
            }
        }
        __syncthreads();
        if (wave == 0) {
            // batch-16 reg reads -> dependent chain in regs -> packed writes.
            float sp[64];
            #pragma unroll
            for (int g = 0; g < 4; ++g) {
                double sv[16];
                #pragma unroll
                for (int k = 0; k < 16; ++k)
                    sv[k] = synbuf[(size_t)(g * 16 + k) * 65 + lane];
                #pragma unroll
                for (int k = 0; k < 16; ++k) {
                    double reset = (mem > 1.0) ? 1.0 : 0.0;
                    mem = 0.9 * mem + sv[k] - reset;
                    sp[g * 16 + k] = ((mem - 1.0) > 0.0) ? 1.0f : 0.0f;
                }
            }
            #pragma unroll
            for (int k4 = 0; k4 < 16; ++k4)
                *(float4*)&spkbuf[lane * 68 + k4 * 4] = make_float4(
                    sp[k4 * 4], sp[k4 * 4 + 1], sp[k4 * 4 + 2], sp[k4 * 4 + 3]);
        }
        __syncthreads();
        {
            const int o = tid >> 3, tg = tid & 7;
            float4 v0 = *(float4*)&spkbuf[o * 68 + tg * 8];
            float4 v1 = *(float4*)&spkbuf[o * 68 + tg * 8 + 4];
            float* dst = outp + (size_t)o * T_DIM + c * 64 + tg * 8;
            *(float4*)&dst[0] = v0;
            *(float4*)&dst[4] = v1;
        }
        __syncthreads();
    }
}

// ---------------- Fallback GEMM: R6 f64-MFMA with probes (proven) ----------
#define BM 128
#define BN 128
#define BK 16
#define LDA 130

__global__ __launch_bounds__(256, 2) void spk_gemm_mfma64p_kernel(
    const float* __restrict__ x, const float* __restrict__ W,
    float* __restrict__ syn_hi, float* __restrict__ syn_lo)
{
    const int tid  = threadIdx.x;
    const int lane = tid & 63;
    const int wave = tid >> 6;
    const int tb = blockIdx.x, ob = blockIdx.y, b = blockIdx.z;

    __shared__ __align__(16) double As[BK][LDA];
    __shared__ __align__(16) double Bs[BK][LDA];

    const v4d zz = {0.0, 0.0, 0.0, 0.0};
    v4d d1 = __builtin_amdgcn_mfma_f64_16x16x4f64((double)lane, 1.0, zz, 0, 0, 0);
    v4d d2 = __builtin_amdgcn_mfma_f64_16x16x4f64(1.0, (double)lane, zz, 0, 0, 0);
    const bool a_h1 = (((int)d1[0] & 3) == 0);
    const bool b_h1 = (((int)d2[0] & 3) == 0);
    int drow[4];
    #pragma unroll
    for (int r = 0; r < 4; ++r) {
        const int v = (int)d1[r];
        drow[r] = (a_h1 ? (v - 96) >> 2 : (v - 6) >> 4) & 15;
    }
    const int am = a_h1 ? (lane & 15) : (lane >> 2);
    const int ak = a_h1 ? (lane >> 4) : (lane & 3);
    const int bn = b_h1 ? (lane & 15) : (lane >> 2);
    const int bk = b_h1 ? (lane >> 4) : (lane & 3);
    const int dcol = lane & 15;

    const int o0 = ob * BM, t0 = tb * BN;
    const float* Wp = W + (size_t)o0 * IN_DIM;
    const float* xp = x + (size_t)b * IN_DIM * T_DIM + t0;
    const int wo = (wave >> 1) * 64, wt = (wave & 1) * 64;

    v4d acc[4][4];
    #pragma unroll
    for (int i = 0; i < 4; ++i)
        #pragma unroll
        for (int j = 0; j < 4; ++j) acc[i][j] = zz;

    const int ar0 = tid / 4, ac = (tid % 4) * 4;
    const int bkr0 = tid / 32, btc = (tid % 32) * 4;

    float4 pa[2], pb[2];
    #pragma unroll
    for (int p = 0; p < 2; ++p) {
        pa[p] = *(const float4*)&Wp[(size_t)(ar0 + p * 64) * IN_DIM + ac];
        pb[p] = *(const float4*)&xp[(size_t)(bkr0 + p * 8) * T_DIM + btc];
    }

    for (int k0 = 0; k0 < IN_DIM; k0 += BK) {
        #pragma unroll
        for (int p = 0; p < 2; ++p) {
            const int r = ar0 + p * 64;
            As[ac + 0][r] = (double)pa[p].x; As[ac + 1][r] = (double)pa[p].y;
            As[ac + 2][r] = (double)pa[p].z; As[ac + 3][r] = (double)pa[p].w;
            const int kr = bkr0 + p * 8;
            Bs[kr][btc + 0] = (double)pb[p].x; Bs[kr][btc + 1] = (double)pb[p].y;
            Bs[kr][btc + 2] = (double)pb[p].z; Bs[kr][btc + 3] = (double)pb[p].w;
        }
        if (k0 + BK < IN_DIM) {
            #pragma unroll
            for (int p = 0; p < 2; ++p) {
                pa[p] = *(const float4*)&Wp[(size_t)(ar0 + p * 64) * IN_DIM + k0 + BK + ac];
                pb[p] = *(const float4*)&xp[(size_t)(bkr0 + p * 8 + k0 + BK) * T_DIM + btc];
            }
        }
        __syncthreads();
        #pragma unroll
        for (int kk = 0; kk < 4; ++kk) {
            const int kra = kk * 4 + ak, krb = kk * 4 + bk;
            double a[4], bb[4];
            #pragma unroll
            for (int i = 0; i < 4; ++i) a[i] = As[kra][wo + i * 16 + am];
            #pragma unroll
            for (int j = 0; j < 4; ++j) bb[j] = Bs[krb][wt + j * 16 + bn];
            #pragma unroll
            for (int i = 0; i < 4; ++i)
                #pragma unroll
                for (int j = 0; j < 4; ++j)
                    acc[i][j] = __builtin_amdgcn_mfma_f64_16x16x4f64(a[i], bb[j], acc[i][j], 0, 0, 0);
        }
        __syncthreads();
    }

    float* ohi = syn_hi + ((size_t)b * OUT_DIM + o0) * T_DIM + t0;
    float* olo = syn_lo + ((size_t)b * OUT_DIM + o0) * T_DIM + t0;
    #pragma unroll
    for (int i = 0; i < 4; ++i)
        #pragma unroll
        for (int j = 0; j < 4; ++j) {
            const int col = wt + j * 16 + dcol;
            #pragma unroll
            for (int r = 0; r < 4; ++r) {
                double s = acc[i][j][r];
                float hi = (float)s;
                float lo = (float)(s - (double)hi);
                const size_t off = (size_t)(wo + i * 16 + drow[r]) * T_DIM + col;
                ohi[off] = hi; olo[off] = lo;
            }
        }
}

// ---------------- scan: f64 LIF, in place over hi (fallback only) ----------
__global__ __launch_bounds__(256) void spk_scan_f64_kernel(
    float* __restrict__ hi, const float* __restrict__ lo)
{
    const int TC = 16;
    __shared__ float thi[256][TC + 1];
    __shared__ float tlo[256][TC + 1];
    const int tid = threadIdx.x;
    const size_t row0 = (size_t)blockIdx.x * 256;

    double mem = 0.0;
    for (int t0 = 0; t0 < T_DIM; t0 += TC) {
        #pragma unroll
        for (int p = 0; p < 4; ++p) {
            int id = tid + p * 256;
            int r = id / 4, c = (id % 4) * 4;
            size_t g = (row0 + r) * T_DIM + t0 + c;
            float4 vh = *(const float4*)&hi[g];
            thi[r][c] = vh.x; thi[r][c+1] = vh.y; thi[r][c+2] = vh.z; thi[r][c+3] = vh.w;
            float4 vl = *(const float4*)&lo[g];
            tlo[r][c] = vl.x; tlo[r][c+1] = vl.y; tlo[r][c+2] = vl.z; tlo[r][c+3] = vl.w;
        }
        __syncthreads();
        float spk[TC];
        #pragma unroll
        for (int t = 0; t < TC; ++t) {
            double s = (double)thi[tid][t] + (double)tlo[tid][t];
            double reset = (mem > 1.0) ? 1.0 : 0.0;
            mem = 0.9 * mem + s - reset;
            spk[t] = ((mem - 1.0) > 0.0) ? 1.0f : 0.0f;
        }
        __syncthreads();
        #pragma unroll
        for (int t = 0; t < TC; ++t) thi[tid][t] = spk[t];
        __syncthreads();
        #pragma unroll
        for (int p = 0; p < 4; ++p) {
            int id = tid + p * 256;
            int r = id / 4, c = (id % 4) * 4;
            float4 v = make_float4(thi[r][c], thi[r][c+1], thi[r][c+2], thi[r][c+3]);
            *(float4*)&hi[(row0 + r) * T_DIM + t0 + c] = v;
        }
        __syncthreads();
    }
}

extern "C" void kernel_launch(void* const* d_in, const int* in_sizes, int n_in,
                              void* d_out, int out_size, void* d_ws, size_t ws_size,
                              hipStream_t stream)
{
    const float* x = (const float*)d_in[0];
    const float* W = (const float*)d_in[1];
    float* hi = (float*)d_out;
    char* ws = (char*)d_ws;
    float* lo = (float*)(ws + LO_OFF);

    if (ws_size >= WS_NEED) {
        signed char* wsl = (signed char*)(ws + WSL_OFF);
        signed char* xsl = (signed char*)(ws + XSL_OFF);
        int* alpha = (int*)(ws + AL_OFF);
        int* beta  = (int*)(ws + BE_OFF);
        float* part = (float*)(ws + PART_OFF);

        k_beta_part<<<dim3(16, B_DIM), dim3(256), 0, stream>>>(x, part);
        k_beta<<<dim3(B_DIM), dim3(256), 0, stream>>>(part, beta);
        k_slice_w<<<dim3(OUT_DIM), dim3(256), 0, stream>>>(W, wsl, alpha);
        k_slice_x<<<dim3(4, 16, B_DIM), dim3(256), 0, stream>>>(x, beta, xsl);
        k_oz_gemm_fused<<<dim3(1024), dim3(512), 0, stream>>>(wsl, xsl, alpha, beta, hi);
    } else {
        spk_gemm_mfma64p_kernel<<<dim3(2, 8, B_DIM), dim3(256), 0, stream>>>(x, W, hi, lo);
        spk_scan_f64_kernel<<<dim3((B_DIM * OUT_DIM) / 256), dim3(256), 0, stream>>>(hi, lo);
    }
}

// Round 9
// 306.853 us; speedup vs baseline: 1.6414x; 1.0788x over previous
//
#include <hip/hip_runtime.h>

// B=64, IN=1024, OUT=1024, T=256
// syn[b,o,t] = sum_i W[o,i]*x[b,i,t]; spikes via f64 LIF scan.
//
// R19 = R18 resubmit (R18 bench died to container infra, no kernel verdict;
// same signature as R13 which passed unchanged on resubmit).
// R18: aux micro-round. (1) slice_w+beta_part merged into one dual-role
// launch (independent inputs; one less gap, overlapped traffic). (2)
// beta_part float4-across-t. (3) slice_x tile load via float4 (ft padded
// to [64][68] for aligned b128 LDS writes; read side stays 2-way/free).
// (4) scan select-form: a=0.9*mem+s; mem=(old>1)?a-1:a — same arithmetic,
// shorter dependent chain.
// Fused GEMM+scan core unchanged from R17 (4-digit Ozaki p+q<=3, 20
// MFMAs/wave-step, triple buffer 3x40KB, counted vmcnt(5), setprio, XCD
// b-swizzle, de-aliased reg scan). Step model (R11-R17, <8% err):
// 1464 MFMA + 1129 LDSread + ~470 DMA + ~420 scan+misc cyc/block-step.
// Fallback: R6 f64-MFMA + standalone scan.

#define B_DIM 64
#define IN_DIM 1024
#define OUT_DIM 1024
#define T_DIM 256

typedef int v4i __attribute__((ext_vector_type(4)));
typedef int v16i __attribute__((ext_vector_type(16)));
typedef double v4d __attribute__((ext_vector_type(4)));

// ---------------- workspace layout (bytes) ----------------
#define LO_OFF   0ull                    // 67108864  f32 syn_lo (fallback only)
#define WSL_OFF  67108864ull             // i8 W frags [p:4][o32:32][ks:32][lane:64][16] = 4MB
#define XSL_OFF  73400320ull             // i8 x frags [q:4][b:64][t32:8][ks:32][lane:64][16] = 67MB
#define AL_OFF   174063616ull            // 4096      i32 alpha_e[1024]
#define BE_OFF   174067712ull            // 65536     i32 beta_e[64][256]
#define PART_OFF 174133248ull            // 1048576   f32 partial maxes [64][16][256]
#define WS_NEED  175181824ull

__device__ __forceinline__ void gload_lds16(const void* g, void* l)
{
    __builtin_amdgcn_global_load_lds(
        (const __attribute__((address_space(1))) void*)g,
        (__attribute__((address_space(3))) void*)l, 16, 0, 0);
}

// Integer digit extraction: fix28 = |x|/2^e_col * 2^28 (truncated), digits =
// 7-bit slices, negated if x<0. Bit-identical to the proven f64 trunc loop.
__device__ __forceinline__ void dig4_extract(unsigned bits, int bem,
                                             signed char* d /*4*/)
{
    const int be = (bits >> 23) & 255;
    unsigned M = (bits & 0x7fffffu) | (be ? 0x800000u : 0u);
    const int sh = be - bem + 4;
    unsigned fix = 0;
    if (sh >= 0) fix = M << sh;
    else if (sh > -32) fix = M >> (-sh);
    int d0 = (fix >> 21) & 127, d1 = (fix >> 14) & 127,
        d2 = (fix >> 7) & 127,  d3 = fix & 127;
    if (bits & 0x80000000u) { d0 = -d0; d1 = -d1; d2 = -d2; d3 = -d3; }
    d[0] = (signed char)d0; d[1] = (signed char)d1;
    d[2] = (signed char)d2; d[3] = (signed char)d3;
}

// ---------------- K1: dual-role aux (slice_w | beta_part) ----------------
// bid<1024: slice_w (o=bid). bid>=1024: beta_part, idx=bid-1024,
// ic=idx&15, b=idx>>4; float4-across-t, 4 i-quarters reduced via LDS.
__global__ __launch_bounds__(256) void k_aux_wx(
    const float* __restrict__ W, signed char* __restrict__ wsl,
    int* __restrict__ alpha_e,
    const float* __restrict__ x, float* __restrict__ part)
{
    __shared__ float red[256];
    __shared__ float wrow[1024];
    __shared__ int se;
    __shared__ float4 bp[4][64];
    const int tid = threadIdx.x;

    if (blockIdx.x < 1024) {
        // ---- slice_w (proven R15) ----
        const int o = blockIdx.x;
        float4 v = *(const float4*)&W[(size_t)o * IN_DIM + tid * 4];
        *(float4*)&wrow[tid * 4] = v;
        float m = fmaxf(fmaxf(fabsf(v.x), fabsf(v.y)), fmaxf(fabsf(v.z), fabsf(v.w)));
        red[tid] = m; __syncthreads();
        for (int s = 128; s > 0; s >>= 1) {
            if (tid < s) red[tid] = fmaxf(red[tid], red[tid + s]);
            __syncthreads();
        }
        if (tid == 0) { int e = 0; if (red[0] > 0.f) frexpf(red[0], &e); se = e; alpha_e[o] = e; }
        __syncthreads();
        if (tid >= 64) return;
        const int bem = se + 126;
        const int ks = tid >> 1, khalf = tid & 1;
        const int k0 = tid * 16;
        const int lane = (o & 31) + 32 * khalf;

        signed char dig[16][4];
        #pragma unroll
        for (int j = 0; j < 16; ++j)
            dig4_extract(__float_as_uint(wrow[k0 + j]), bem, dig[j]);

        #pragma unroll
        for (int p = 0; p < 4; ++p) {
            int w[4];
            #pragma unroll
            for (int g = 0; g < 4; ++g)
                w[g] = (dig[4*g][p] & 0xff) | ((dig[4*g+1][p] & 0xff) << 8) |
                       ((dig[4*g+2][p] & 0xff) << 16) | ((dig[4*g+3][p] & 0xff) << 24);
            const size_t base =
                (((size_t)p * 32 + (o >> 5)) * 32 + ks) * 1024 + lane * 16;
            *(v4i*)&wsl[base] = (v4i){w[0], w[1], w[2], w[3]};
        }
    } else {
        // ---- beta_part, float4 ----
        const int idx = blockIdx.x - 1024;
        const int ic = idx & 15, b = idx >> 4;
        const int quarter = tid >> 6, t4 = (tid & 63) * 4;
        const float* p = x + ((size_t)b * IN_DIM + ic * 64 + quarter * 16) * T_DIM + t4;
        float4 m4 = make_float4(0.f, 0.f, 0.f, 0.f);
        #pragma unroll
        for (int r = 0; r < 16; ++r) {
            float4 v = *(const float4*)&p[(size_t)r * T_DIM];
            m4.x = fmaxf(m4.x, fabsf(v.x)); m4.y = fmaxf(m4.y, fabsf(v.y));
            m4.z = fmaxf(m4.z, fabsf(v.z)); m4.w = fmaxf(m4.w, fabsf(v.w));
        }
        bp[quarter][tid & 63] = m4;
        __syncthreads();
        if (tid < 64) {
            float4 a = bp[0][tid], b4 = bp[1][tid], c = bp[2][tid], d = bp[3][tid];
            float4 r;
            r.x = fmaxf(fmaxf(a.x, b4.x), fmaxf(c.x, d.x));
            r.y = fmaxf(fmaxf(a.y, b4.y), fmaxf(c.y, d.y));
            r.z = fmaxf(fmaxf(a.z, b4.z), fmaxf(c.z, d.z));
            r.w = fmaxf(fmaxf(a.w, b4.w), fmaxf(c.w, d.w));
            *(float4*)&part[((size_t)b * 16 + ic) * T_DIM + tid * 4] = r;
        }
    }
}

// ---------------- K1b: beta exponents (proven) ----------------
__global__ __launch_bounds__(256) void k_beta(const float* __restrict__ part,
                                              int* __restrict__ beta_e)
{
    const int b = blockIdx.x, t = threadIdx.x;
    float m = 0.f;
    #pragma unroll
    for (int ic = 0; ic < 16; ++ic)
        m = fmaxf(m, part[((size_t)b * 16 + ic) * T_DIM + t]);
    int e = 0;
    if (m > 0.f) frexpf(m, &e);   // |x|/2^e < 1
    beta_e[b * T_DIM + t] = e;
}

// ---------------- K2: slice x -> fragment order (4 digits, int path) -------
__global__ __launch_bounds__(256) void k_slice_x(const float* __restrict__ x,
    const int* __restrict__ beta_e, signed char* __restrict__ xsl)
{
    __shared__ float ft[64][68];   // 68: float4-aligned rows, read 2-way free
    const int tb = blockIdx.x;    // 0..3
    const int ib = blockIdx.y;    // 0..15
    const int b  = blockIdx.z;
    const int tid = threadIdx.x;
    const int t0 = tb * 64, i0 = ib * 64;
    #pragma unroll
    for (int p = 0; p < 4; ++p) {
        int id4 = tid + p * 256;           // 0..1023 float4 slots
        int il = id4 >> 4, c4 = (id4 & 15) * 4;
        float4 v = *(const float4*)&x[((size_t)b * IN_DIM + i0 + il) * T_DIM + t0 + c4];
        *(float4*)&ft[il][c4] = v;
    }
    __syncthreads();

    const int t32l = tid >> 7;
    const int ksl  = (tid >> 6) & 1;
    const int lane = tid & 63;
    const int t_local = t32l * 32 + (lane & 31);
    const int k_local = ksl * 32 + (lane >> 5) * 16;
    const int e = beta_e[b * T_DIM + t0 + t_local];
    const int bem = e + 126;

    signed char dig[16][4];
    #pragma unroll
    for (int j = 0; j < 16; ++j)
        dig4_extract(__float_as_uint(ft[k_local + j][t_local]), bem, dig[j]);

    #pragma unroll
    for (int p = 0; p < 4; ++p) {
        int w[4];
        #pragma unroll
        for (int g = 0; g < 4; ++g)
            w[g] = (dig[4*g][p] & 0xff) | ((dig[4*g+1][p] & 0xff) << 8) |
                   ((dig[4*g+2][p] & 0xff) << 16) | ((dig[4*g+3][p] & 0xff) << 24);
        const size_t base =
            ((((size_t)p * B_DIM + b) * 8 + (tb * 2 + t32l)) * 32 + (ib * 2 + ksl)) * 1024
            + lane * 16;
        *(v4i*)&xsl[base] = (v4i){w[0], w[1], w[2], w[3]};
    }
}

// ---------------- K4: fused Ozaki i8 GEMM + LIF scan ----------------
// Block 64(o)x256(t), 1D grid 1024 with XCD swizzle: ob=bid>>6, r=bid&63,
// b=(r&7)*8+(r>>3). 8 waves: woh=wave>>2 (o sub), wtq=wave&3 (t quarter).
// Wave tile 32x64, 20 MFMAs/step. LDS buffer (40KB): 40 segments of 1KB;
// segment s = 8j + wave. s<8 -> A [p=s>>1][osub=s&1]; s>=8 -> u=s-8,
// B [q=u>>3][t32=u&7]. vmcnt ledger: 5 loads/thread/step, vmcnt(5) steady,
// drain once at kt=30 (proven R11-R17 skeleton).
// Epilogue: 4 t-chunks; synbuf f64 [t:64][o:65]; wave 0 scans with batch-16
// reg reads, select-form update, ALL spikes in regs, float4 writes at end.
#define OZ_LOADS(PF)                                                        \
    {                                                                       \
        _Pragma("unroll")                                                   \
        for (int j = 0; j < 5; ++j) {                                       \
            gload_lds16(gp[j], &LB[PF][lbase + j * 8192]);                  \
            gp[j] += 1024;                                                  \
        }                                                                   \
    }

#define OZ_MATH(CUR)                                                        \
    {                                                                       \
        const signed char* base_ = LB[CUR];                                 \
        v4i af[4];                                                          \
        _Pragma("unroll")                                                   \
        for (int p = 0; p < 4; ++p)                                         \
            af[p] = *(const v4i*)(base_ + p * 2048 + aoffm);                \
        __builtin_amdgcn_s_setprio(1);                                      \
        _Pragma("unroll")                                                   \
        for (int q = 0; q < 4; ++q) {                                       \
            v4i b0 = *(const v4i*)(base_ + q * 8192 + boffm);               \
            v4i b1 = *(const v4i*)(base_ + q * 8192 + boffm + 1024);        \
            _Pragma("unroll")                                               \
            for (int p = 0; p + q < 4; ++p) {                               \
                accA[p + q] = __builtin_amdgcn_mfma_i32_32x32x32_i8(        \
                    af[p], b0, accA[p + q], 0, 0, 0);                       \
                accB[p + q] = __builtin_amdgcn_mfma_i32_32x32x32_i8(        \
                    af[p], b1, accB[p + q], 0, 0, 0);                       \
            }                                                               \
        }                                                                   \
        __builtin_amdgcn_s_setprio(0);                                      \
    }

#define VMBAR(N)                                                            \
    do {                                                                    \
        asm volatile("s_waitcnt vmcnt(" #N ")" ::: "memory");               \
        __builtin_amdgcn_s_barrier();                                       \
    } while (0)

__global__ __launch_bounds__(512, 2) void k_oz_gemm_fused(
    const signed char* __restrict__ wsl, const signed char* __restrict__ xsl,
    const int* __restrict__ alpha_e, const int* __restrict__ beta_e,
    float* __restrict__ out)
{
    __shared__ __align__(16) signed char LB[3][40960];

    const int tid = threadIdx.x;
    const int lane = tid & 63, wave = tid >> 6;    // wave 0..7
    const int bid = blockIdx.x;
    const int ob = bid >> 6;                       // 0..15 (o block of 64)
    const int rr = bid & 63;
    const int b  = ((rr & 7) << 3) + (rr >> 3);    // bijective XCD swizzle
    const int o0 = ob * 64;
    const int woh = wave >> 2;   // o sub 0..1 (32 rows each)
    const int wtq = wave & 3;    // t quarter 0..3 (64 cols each)
    const int l16 = lane * 16;

    v16i accA[4], accB[4];
    #pragma unroll
    for (int s = 0; s < 4; ++s) {
        accA[s] = (v16i){0,0,0,0,0,0,0,0,0,0,0,0,0,0,0,0};
        accB[s] = (v16i){0,0,0,0,0,0,0,0,0,0,0,0,0,0,0,0};
    }

    // Staging pointers: segment s = 8j + wave.
    // wsl addr = (p<<20) + (o32<<15) + (kt<<10) + lane*16, o32 = 2*ob + osub.
    // xsl addr = (q<<24) + (b<<18) + (t32<<15) + (kt<<10) + lane*16.
    const signed char* gp[5];
    #pragma unroll
    for (int j = 0; j < 5; ++j) {
        const int s = 8 * j + wave;
        if (s < 8) {
            gp[j] = wsl + ((size_t)(s >> 1) << 20)
                        + ((size_t)(2 * ob + (s & 1)) << 15) + l16;
        } else {
            const int u = s - 8;
            gp[j] = xsl + ((size_t)(u >> 3) << 24) + ((size_t)b << 18)
                        + ((size_t)(u & 7) << 15) + l16;
        }
    }
    const int lbase = wave * 1024;   // segment s LDS offset = s*1024

    // Math-side LDS offsets.
    const int aoffm = woh * 1024 + l16;            // + p*2048 (A region [0,8192))
    const int boffm = 8192 + wtq * 2048 + l16;     // + q*8192 (B region)

    // prologue: kt=0 -> LB[0], kt=1 -> LB[1]; retire kt=0 (vmcnt 10->5).
    OZ_LOADS(0)
    OZ_LOADS(1)
    VMBAR(5);

    // steady state: kt = 0..29, buffers rotate (0,1,2). Never drain to 0.
    #pragma unroll 1
    for (int it = 0; it < 10; ++it) {
        OZ_LOADS(2) OZ_MATH(0) VMBAR(5);
        OZ_LOADS(0) OZ_MATH(1) VMBAR(5);
        OZ_LOADS(1) OZ_MATH(2) VMBAR(5);
    }
    // kt=30: drain kt=31's 5 loads, last barrier.
    OZ_MATH(0) VMBAR(0);
    // kt=31: registers only.
    OZ_MATH(1)

    // Runtime D-placement probes (R6/R7 technique).
    const int lr = lane & 31;
    const int rv = (lr + 1) * 0x01010101;
    const v4i pav  = {rv, rv, rv, rv};
    const v4i onev = {0x01010101, 0x01010101, 0x01010101, 0x01010101};
    const v16i z = (v16i){0,0,0,0,0,0,0,0,0,0,0,0,0,0,0,0};
    v16i d1 = __builtin_amdgcn_mfma_i32_32x32x32_i8(pav, onev, z, 0, 0, 0);
    v16i d2 = __builtin_amdgcn_mfma_i32_32x32x32_i8(onev, pav, z, 0, 0, 0);

    const int col = (d2[0] >> 5) - 1;            // 0..31 within tile
    const int gtA = wtq * 64 + col;              // global t of accA column
    const int gtB = gtA + 32;                    // accB column
    const int ebA = beta_e[b * T_DIM + gtA];
    const int ebB = beta_e[b * T_DIM + gtB];

    // Exact f64 syn per (r, A/B); acc dies here.
    const double C0 = 0x1p-14, C1 = 0x1p-21, C2 = 0x1p-28, C3 = 0x1p-35;
    double synA_[16], synB_[16];
    int go_[16];
    #pragma unroll
    for (int r = 0; r < 16; ++r) {
        const int row = (d1[r] >> 5) - 1;        // 0..31 within tile
        const int go = woh * 32 + row;
        go_[r] = go;
        const int ea = alpha_e[o0 + go];
        double vA = (double)accA[0][r] * C0 + (double)accA[1][r] * C1 +
                    (double)accA[2][r] * C2 + (double)accA[3][r] * C3;
        double vB = (double)accB[0][r] * C0 + (double)accB[1][r] * C1 +
                    (double)accB[2][r] * C2 + (double)accB[3][r] * C3;
        synA_[r] = ldexp(vA, ea + ebA);
        synB_[r] = ldexp(vB, ea + ebB);
    }

    // ---- fused LIF scan over 4 t-chunks of 64 ----
    double* synbuf = (double*)&LB[0][0];   // [t:64][o:65]
    float*  spkbuf = (float*)&LB[1][0];    // [o:64][68] (float4-aligned rows)
    float*  outp = out + ((size_t)b * OUT_DIM + o0) * T_DIM;
    double mem = 0.0;                      // valid in wave 0 lanes (o-rows)

    __syncthreads();
    #pragma unroll 1
    for (int c = 0; c < 4; ++c) {
        if (wtq == c) {
            #pragma unroll
            for (int r = 0; r < 16; ++r) {
                synbuf[(size_t)col * 65 + go_[r]]        = synA_[r];
                synbuf[(size_t)(col + 32) * 65 + go_[r]] = synB_[r];
            }
        }
        __syncthreads();
        if (wave == 0) {
            // batch-16 reg reads -> short select-form chain -> packed writes.
            float sp[64];
            #pragma unroll
            for (int g = 0; g < 4; ++g) {
                double sv[16];
                #pragma unroll
                for (int k = 0; k < 16; ++k)
                    sv[k] = synbuf[(size_t)(g * 16 + k) * 65 + lane];
                #pragma unroll
                for (int k = 0; k < 16; ++k) {
                    double a = 0.9 * mem + sv[k];          // same eval order
                    mem = (mem > 1.0) ? (a - 1.0) : a;     // reset uses OLD mem
                    sp[g * 16 + k] = (mem > 1.0) ? 1.0f : 0.0f;
                }
            }
            #pragma unroll
            for (int k4 = 0; k4 < 16; ++k4)
                *(float4*)&spkbuf[lane * 68 + k4 * 4] = make_float4(
                    sp[k4 * 4], sp[k4 * 4 + 1], sp[k4 * 4 + 2], sp[k4 * 4 + 3]);
        }
        __syncthreads();
        {
            const int o = tid >> 3, tg = tid & 7;
            float4 v0 = *(float4*)&spkbuf[o * 68 + tg * 8];
            float4 v1 = *(float4*)&spkbuf[o * 68 + tg * 8 + 4];
            float* dst = outp + (size_t)o * T_DIM + c * 64 + tg * 8;
            *(float4*)&dst[0] = v0;
            *(float4*)&dst[4] = v1;
        }
        __syncthreads();
    }
}

// ---------------- Fallback GEMM: R6 f64-MFMA with probes (proven) ----------
#define BM 128
#define BN 128
#define BK 16
#define LDA 130

__global__ __launch_bounds__(256, 2) void spk_gemm_mfma64p_kernel(
    const float* __restrict__ x, const float* __restrict__ W,
    float* __restrict__ syn_hi, float* __restrict__ syn_lo)
{
    const int tid  = threadIdx.x;
    const int lane = tid & 63;
    const int wave = tid >> 6;
    const int tb = blockIdx.x, ob = blockIdx.y, b = blockIdx.z;

    __shared__ __align__(16) double As[BK][LDA];
    __shared__ __align__(16) double Bs[BK][LDA];

    const v4d zz = {0.0, 0.0, 0.0, 0.0};
    v4d d1 = __builtin_amdgcn_mfma_f64_16x16x4f64((double)lane, 1.0, zz, 0, 0, 0);
    v4d d2 = __builtin_amdgcn_mfma_f64_16x16x4f64(1.0, (double)lane, zz, 0, 0, 0);
    const bool a_h1 = (((int)d1[0] & 3) == 0);
    const bool b_h1 = (((int)d2[0] & 3) == 0);
    int drow[4];
    #pragma unroll
    for (int r = 0; r < 4; ++r) {
        const int v = (int)d1[r];
        drow[r] = (a_h1 ? (v - 96) >> 2 : (v - 6) >> 4) & 15;
    }
    const int am = a_h1 ? (lane & 15) : (lane >> 2);
    const int ak = a_h1 ? (lane >> 4) : (lane & 3);
    const int bn = b_h1 ? (lane & 15) : (lane >> 2);
    const int bk = b_h1 ? (lane >> 4) : (lane & 3);
    const int dcol = lane & 15;

    const int o0 = ob * BM, t0 = tb * BN;
    const float* Wp = W + (size_t)o0 * IN_DIM;
    const float* xp = x + (size_t)b * IN_DIM * T_DIM + t0;
    const int wo = (wave >> 1) * 64, wt = (wave & 1) * 64;

    v4d acc[4][4];
    #pragma unroll
    for (int i = 0; i < 4; ++i)
        #pragma unroll
        for (int j = 0; j < 4; ++j) acc[i][j] = zz;

    const int ar0 = tid / 4, ac = (tid % 4) * 4;
    const int bkr0 = tid / 32, btc = (tid % 32) * 4;

    float4 pa[2], pb[2];
    #pragma unroll
    for (int p = 0; p < 2; ++p) {
        pa[p] = *(const float4*)&Wp[(size_t)(ar0 + p * 64) * IN_DIM + ac];
        pb[p] = *(const float4*)&xp[(size_t)(bkr0 + p * 8) * T_DIM + btc];
    }

    for (int k0 = 0; k0 < IN_DIM; k0 += BK) {
        #pragma unroll
        for (int p = 0; p < 2; ++p) {
            const int r = ar0 + p * 64;
            As[ac + 0][r] = (double)pa[p].x; As[ac + 1][r] = (double)pa[p].y;
            As[ac + 2][r] = (double)pa[p].z; As[ac + 3][r] = (double)pa[p].w;
            const int kr = bkr0 + p * 8;
            Bs[kr][btc + 0] = (double)pb[p].x; Bs[kr][btc + 1] = (double)pb[p].y;
            Bs[kr][btc + 2] = (double)pb[p].z; Bs[kr][btc + 3] = (double)pb[p].w;
        }
        if (k0 + BK < IN_DIM) {
            #pragma unroll
            for (int p = 0; p < 2; ++p) {
                pa[p] = *(const float4*)&Wp[(size_t)(ar0 + p * 64) * IN_DIM + k0 + BK + ac];
                pb[p] = *(const float4*)&xp[(size_t)(bkr0 + p * 8 + k0 + BK) * T_DIM + btc];
            }
        }
        __syncthreads();
        #pragma unroll
        for (int kk = 0; kk < 4; ++kk) {
            const int kra = kk * 4 + ak, krb = kk * 4 + bk;
            double a[4], bb[4];
            #pragma unroll
            for (int i = 0; i < 4; ++i) a[i] = As[kra][wo + i * 16 + am];
            #pragma unroll
            for (int j = 0; j < 4; ++j) bb[j] = Bs[krb][wt + j * 16 + bn];
            #pragma unroll
            for (int i = 0; i < 4; ++i)
                #pragma unroll
                for (int j = 0; j < 4; ++j)
                    acc[i][j] = __builtin_amdgcn_mfma_f64_16x16x4f64(a[i], bb[j], acc[i][j], 0, 0, 0);
        }
        __syncthreads();
    }

    float* ohi = syn_hi + ((size_t)b * OUT_DIM + o0) * T_DIM + t0;
    float* olo = syn_lo + ((size_t)b * OUT_DIM + o0) * T_DIM + t0;
    #pragma unroll
    for (int i = 0; i < 4; ++i)
        #pragma unroll
        for (int j = 0; j < 4; ++j) {
            const int col = wt + j * 16 + dcol;
            #pragma unroll
            for (int r = 0; r < 4; ++r) {
                double s = acc[i][j][r];
                float hi = (float)s;
                float lo = (float)(s - (double)hi);
                const size_t off = (size_t)(wo + i * 16 + drow[r]) * T_DIM + col;
                ohi[off] = hi; olo[off] = lo;
            }
        }
}

// ---------------- scan: f64 LIF, in place over hi (fallback only) ----------
__global__ __launch_bounds__(256) void spk_scan_f64_kernel(
    float* __restrict__ hi, const float* __restrict__ lo)
{
    const int TC = 16;
    __shared__ float thi[256][TC + 1];
    __shared__ float tlo[256][TC + 1];
    const int tid = threadIdx.x;
    const size_t row0 = (size_t)blockIdx.x * 256;

    double mem = 0.0;
    for (int t0 = 0; t0 < T_DIM; t0 += TC) {
        #pragma unroll
        for (int p = 0; p < 4; ++p) {
            int id = tid + p * 256;
            int r = id / 4, c = (id % 4) * 4;
            size_t g = (row0 + r) * T_DIM + t0 + c;
            float4 vh = *(const float4*)&hi[g];
            thi[r][c] = vh.x; thi[r][c+1] = vh.y; thi[r][c+2] = vh.z; thi[r][c+3] = vh.w;
            float4 vl = *(const float4*)&lo[g];
            tlo[r][c] = vl.x; tlo[r][c+1] = vl.y; tlo[r][c+2] = vl.z; tlo[r][c+3] = vl.w;
        }
        __syncthreads();
        float spk[TC];
        #pragma unroll
        for (int t = 0; t < TC; ++t) {
            double s = (double)thi[tid][t] + (double)tlo[tid][t];
            double reset = (mem > 1.0) ? 1.0 : 0.0;
            mem = 0.9 * mem + s - reset;
            spk[t] = ((mem - 1.0) > 0.0) ? 1.0f : 0.0f;
        }
        __syncthreads();
        #pragma unroll
        for (int t = 0; t < TC; ++t) thi[tid][t] = spk[t];
        __syncthreads();
        #pragma unroll
        for (int p = 0; p < 4; ++p) {
            int id = tid + p * 256;
            int r = id / 4, c = (id % 4) * 4;
            float4 v = make_float4(thi[r][c], thi[r][c+1], thi[r][c+2], thi[r][c+3]);
            *(float4*)&hi[(row0 + r) * T_DIM + t0 + c] = v;
        }
        __syncthreads();
    }
}

extern "C" void kernel_launch(void* const* d_in, const int* in_sizes, int n_in,
                              void* d_out, int out_size, void* d_ws, size_t ws_size,
                              hipStream_t stream)
{
    const float* x = (const float*)d_in[0];
    const float* W = (const float*)d_in[1];
    float* hi = (float*)d_out;
    char* ws = (char*)d_ws;
    float* lo = (float*)(ws + LO_OFF);

    if (ws_size >= WS_NEED) {
        signed char* wsl = (signed char*)(ws + WSL_OFF);
        signed char* xsl = (signed char*)(ws + XSL_OFF);
        int* alpha = (int*)(ws + AL_OFF);
        int* beta  = (int*)(ws + BE_OFF);
        float* part = (float*)(ws + PART_OFF);

        k_aux_wx<<<dim3(2048), dim3(256), 0, stream>>>(W, wsl, alpha, x, part);
        k_beta<<<dim3(B_DIM), dim3(256), 0, stream>>>(part, beta);
        k_slice_x<<<dim3(4, 16, B_DIM), dim3(256), 0, stream>>>(x, beta, xsl);
        k_oz_gemm_fused<<<dim3(1024), dim3(512), 0, stream>>>(wsl, xsl, alpha, beta, hi);
    } else {
        spk_gemm_mfma64p_kernel<<<dim3(2, 8, B_DIM), dim3(256), 0, stream>>>(x, W, hi, lo);
        spk_scan_f64_kernel<<<dim3((B_DIM * OUT_DIM) / 256), dim3(256), 0, stream>>>(hi, lo);
    }
}